// Round 17
// baseline (460.613 us; speedup 1.0000x reference)
//
#include <hip/hip_runtime.h>
#include <math.h>

#define BN_EPS 1e-5f
#define EPT 16
#define MS_THREADS 512
#define EPB (MS_THREADS * EPT)   // 8192 edges per mscat block
#define BKT_SHIFT 8              // 256 nodes per bucket
#define BKT_CAP 10240            // fixed per-bucket edge capacity (mean 8192)
#define SS_CAP 11264             // ssrc per-bucket stride (padded lists, mult of 4)

typedef float f32x2 __attribute__((ext_vector_type(2)));

// fp8 e4m3 (OCP) helpers — gfx950 HW converters
__device__ inline f32x2 fp8_lo(unsigned int u) {
    return __builtin_amdgcn_cvt_pk_f32_fp8(u, false);   // bytes 0,1 -> 2 f32
}
__device__ inline f32x2 fp8_hi(unsigned int u) {
    return __builtin_amdgcn_cvt_pk_f32_fp8(u, true);    // bytes 2,3 -> 2 f32
}
__device__ inline unsigned short pack_fp8x2(float a, float b) {
    return (unsigned short)(__builtin_amdgcn_cvt_pk_fp8_f32(a, b, 0, false) & 0xFFFFu);
}

// bf16 helpers (RNE pack, shift unpack)
__device__ inline unsigned int f2bf(float f) {
    union { float f; unsigned int i; } x; x.f = f;
    unsigned int r = x.i + 0x7fffu + ((x.i >> 16) & 1u);
    return r >> 16;
}
__device__ inline float u2f(unsigned int u) {
    union { unsigned int i; float f; } x; x.i = u; return x.f;
}

// ---------------- CSR construction (bucketed, fixed-capacity) ----------------

__global__ void k_binit(int* __restrict__ bcur, int nbkt) {
    int i = blockIdx.x * 256 + threadIdx.x;
    if (i < nbkt) bcur[i] = i * BKT_CAP;
}

// scatter packed (src | dlo<<24) into fixed-capacity buckets; int4 edge loads.
__global__ void k_mscat(const int* __restrict__ src, const int* __restrict__ dst,
                        int* __restrict__ bcur, unsigned int* __restrict__ ebuf,
                        int E, int nbkt) {
    __shared__ int hist[512];
    __shared__ int basel[512];
    int t = threadIdx.x;  // 512
    for (int i = t; i < nbkt; i += MS_THREADS) hist[i] = 0;
    __syncthreads();
    int e0 = blockIdx.x * EPB;
    const int4* src4 = (const int4*)src;
    const int4* dst4 = (const int4*)dst;
    int es[EPT], ed[EPT];
#pragma unroll
    for (int k = 0; k < EPT / 4; k++) {
        int i4 = (e0 >> 2) + t + k * MS_THREADS;
        int ebase = i4 << 2;
        if (ebase + 3 < E) {
            int4 sv = src4[i4];
            int4 dv = dst4[i4];
            es[4 * k + 0] = sv.x; ed[4 * k + 0] = dv.x;
            es[4 * k + 1] = sv.y; ed[4 * k + 1] = dv.y;
            es[4 * k + 2] = sv.z; ed[4 * k + 2] = dv.z;
            es[4 * k + 3] = sv.w; ed[4 * k + 3] = dv.w;
        } else {
#pragma unroll
            for (int j = 0; j < 4; j++) {
                int e = ebase + j;
                if (e < E) { es[4 * k + j] = src[e]; ed[4 * k + j] = dst[e]; }
                else { es[4 * k + j] = 0; ed[4 * k + j] = -1; }
            }
        }
    }
#pragma unroll
    for (int k = 0; k < EPT; k++)
        if (ed[k] >= 0) atomicAdd(&hist[ed[k] >> BKT_SHIFT], 1);
    __syncthreads();
    for (int i = t; i < nbkt; i += MS_THREADS) {
        int h = hist[i];
        basel[i] = h ? atomicAdd(&bcur[i], h) : 0;
    }
    __syncthreads();
#pragma unroll
    for (int k = 0; k < EPT; k++) {
        if (ed[k] >= 0) {
            int bkt = ed[k] >> BKT_SHIFT;
            int pos = atomicAdd(&basel[bkt], 1);
            if (pos < (bkt + 1) * BKT_CAP)
                ebuf[pos] = (unsigned int)es[k] | ((unsigned int)(ed[k] & 255) << 24);
        }
    }
}

// per-bucket finalize: padded counts/scan, coalesced cnt/isq/rs, sentinel pads,
// place ssrc. Both ebuf passes use uint4 loads.
__global__ void k_bfin(const unsigned int* __restrict__ ebuf, const int* __restrict__ bcur,
                       int* __restrict__ cnt, float* __restrict__ isq, int* __restrict__ rs,
                       int* __restrict__ ssrc, int N) {
    __shared__ int h[256];
    __shared__ int sc[256];
    __shared__ int curl[256];
    int b = blockIdx.x;
    int t = threadIdx.x;  // 512 threads
    int base = b << 8;
    int s0 = b * BKT_CAP;
    int s0s = b * SS_CAP;
    int s1 = bcur[b];
    if (s1 > s0 + BKT_CAP) s1 = s0 + BKT_CAP;
    const uint4* eb4 = (const uint4*)ebuf;
    if (t < 256) h[t] = 0;
    __syncthreads();
    for (int i4 = (s0 >> 2) + t; (i4 << 2) < s1; i4 += 512) {
        int e = i4 << 2;
        uint4 w = eb4[i4];
        if (e + 3 < s1) {
            atomicAdd(&h[w.x >> 24], 1);
            atomicAdd(&h[w.y >> 24], 1);
            atomicAdd(&h[w.z >> 24], 1);
            atomicAdd(&h[w.w >> 24], 1);
        } else {
            if (e + 0 < s1) atomicAdd(&h[w.x >> 24], 1);
            if (e + 1 < s1) atomicAdd(&h[w.y >> 24], 1);
            if (e + 2 < s1) atomicAdd(&h[w.z >> 24], 1);
        }
    }
    __syncthreads();
    int cp = 0;
    if (t < 256) { cp = (h[t] + 3) & ~3; sc[t] = cp; }
    __syncthreads();
    int x = cp;
    for (int off = 1; off < 256; off <<= 1) {
        int y = (t < 256 && t >= off) ? sc[t - off] : 0;
        __syncthreads();
        if (t < 256) { x += y; sc[t] = x; }
        __syncthreads();
    }
    if (t < 256) {
        int node = base + t;
        if (node < N) {
            int c = h[t];
            int start = s0s + sc[t] - cp;
            cnt[node] = cp;
            isq[node] = rsqrtf((float)c + 1.0f);
            rs[node] = start;
            curl[t] = start;
            for (int p = c; p < cp; p++) ssrc[start + p] = N;
        }
    }
    __syncthreads();
    for (int i4 = (s0 >> 2) + t; (i4 << 2) < s1; i4 += 512) {
        int e = i4 << 2;
        uint4 w = eb4[i4];
        if (e + 0 < s1) { int p = atomicAdd(&curl[w.x >> 24], 1); ssrc[p] = (int)(w.x & 0x00FFFFFFu); }
        if (e + 1 < s1) { int p = atomicAdd(&curl[w.y >> 24], 1); ssrc[p] = (int)(w.y & 0x00FFFFFFu); }
        if (e + 2 < s1) { int p = atomicAdd(&curl[w.z >> 24], 1); ssrc[p] = (int)(w.z & 0x00FFFFFFu); }
        if (e + 3 < s1) { int p = atomicAdd(&curl[w.w >> 24], 1); ssrc[p] = (int)(w.w & 0x00FFFFFFu); }
    }
}

// ---------------- BN prefold: sc = g*rsqrt(v+eps), sh = (b-m)*sc + be ----------------
__global__ void k_prep(const float* b1, const float* g1, const float* be1,
                       const float* m1, const float* v1,
                       const float* b2, const float* g2, const float* be2,
                       const float* m2, const float* v2,
                       const float* b3, const float* g3, const float* be3,
                       const float* m3, const float* v3,
                       const float* b4, float* __restrict__ scsh) {
    int t = threadIdx.x;  // 256
    int layer = t >> 6, ch = t & 63;
    float sc, sh;
    if (layer == 3) { sc = 1.f; sh = b4[ch]; }
    else {
        const float* bb = layer == 0 ? b1 : layer == 1 ? b2 : b3;
        const float* gg = layer == 0 ? g1 : layer == 1 ? g2 : g3;
        const float* ee = layer == 0 ? be1 : layer == 1 ? be2 : be3;
        const float* mm = layer == 0 ? m1 : layer == 1 ? m2 : m3;
        const float* vv = layer == 0 ? v1 : layer == 1 ? v2 : v3;
        sc = gg[ch] * rsqrtf(vv[ch] + BN_EPS);
        sh = (bb[ch] - mm[ch]) * sc + ee[ch];
    }
    scsh[layer * 128 + ch] = sc;
    scsh[layer * 128 + 64 + ch] = sh;
}

// ---------------- dense transforms (pre-scaled by isq[node], fp8 output) ----------------

__global__ void k_transform3(const float* __restrict__ x, const float* __restrict__ W,
                             const float* __restrict__ isq, unsigned short* __restrict__ out,
                             int N) {
    __shared__ float Ws[192];
    __shared__ float xs[4][4];
    int c = threadIdx.x, ty = threadIdx.y;
    int t = ty * 64 + c;
    if (t < 192) Ws[t] = W[t];
    int node = blockIdx.x * 4 + ty;
    if (c < 3 && node < N) xs[ty][c] = x[node * 3 + c];
    __syncthreads();
    if (node >= N) return;
    float acc = xs[ty][0] * Ws[c] + xs[ty][1] * Ws[64 + c] + xs[ty][2] * Ws[128 + c];
    acc *= isq[node];
    float partner = __shfl_xor(acc, 1);
    if (!(c & 1)) out[node * 32 + (c >> 1)] = pack_fp8x2(acc, partner);
}

// 32 nodes per block; bf16 trunk input; W transposed in LDS; fp8 pair-packed output.
__global__ void k_transform64(const unsigned short* __restrict__ in, const float* __restrict__ W,
                              const float* __restrict__ isq, unsigned short* __restrict__ out,
                              int N) {
    __shared__ float Wt[64 * 68];
    __shared__ float hs[32][64];
    int c = threadIdx.x, ty = threadIdx.y;  // 64 x 4
    int t = ty * 64 + c;
    for (int i = t; i < 4096; i += 256) {
        int k = i >> 6, cc = i & 63;
        Wt[cc * 68 + k] = W[i];
    }
    int base = blockIdx.x * 32;
    for (int r = ty; r < 32; r += 4) {
        int node = base + r;
        hs[r][c] = (node < N) ? u2f(((unsigned int)in[node * 64 + c]) << 16) : 0.f;
    }
    __syncthreads();
    const float4* wrow = (const float4*)&Wt[c * 68];
    for (int r = ty; r < 32; r += 4) {
        int node = base + r;
        if (node >= N) continue;
        const float4* hrow = (const float4*)&hs[r][0];
        float acc = 0.f;
#pragma unroll
        for (int k4 = 0; k4 < 16; k4++) {
            float4 wv = wrow[k4];
            float4 hv = hrow[k4];
            acc = fmaf(hv.x, wv.x, acc);
            acc = fmaf(hv.y, wv.y, acc);
            acc = fmaf(hv.z, wv.z, acc);
            acc = fmaf(hv.w, wv.w, acc);
        }
        acc *= isq[node];
        float partner = __shfl_xor(acc, 1);
        if (!(c & 1)) out[node * 32 + (c >> 1)] = pack_fp8x2(acc, partner);
    }
}

// ---------------- fused CSR aggregate + prefolded BN + ReLU + residual ----------------
// 16 lanes/edge, 4 fp8 channels per lane (dword gather, 64B rows); int4 index
// chunks; depth-4 gather chains. bf16 trunk in/out. MODE 0: relu; 1: relu+res; 2: plain.
template <int MODE>
__global__ void k_rowwave(const unsigned int* __restrict__ ht8, const int* __restrict__ rs,
                          const int* __restrict__ cnt, const int* __restrict__ ssrc,
                          const float* __restrict__ isq,
                          const float* __restrict__ sc, const float* __restrict__ sh,
                          const unsigned short* __restrict__ xres,
                          unsigned short* __restrict__ out, int N) {
    int tid = threadIdx.x;
    int lane = tid & 63;
    int node = (blockIdx.x << 2) + (tid >> 6);
    if (node >= N) return;
    int grp = lane >> 4;   // edge-group 0..3
    int cl = lane & 15;    // channel quad (4 fp8 = 1 dword)
    f32x2 a0l = {0.f, 0.f}, a0h = {0.f, 0.f};
    f32x2 a1l = {0.f, 0.f}, a1h = {0.f, 0.f};
    f32x2 a2l = {0.f, 0.f}, a2h = {0.f, 0.f};
    f32x2 a3l = {0.f, 0.f}, a3h = {0.f, 0.f};
    if (grp == 0) {  // self-loop
        unsigned int u = ht8[node * 16 + cl];
        a0l += fp8_lo(u); a0h += fp8_hi(u);
    }
    int st = rs[node];
    int nch = cnt[node] >> 2;
    const int4* ip = (const int4*)(ssrc + st);
    for (int ch = grp; ch < nch; ch += 4) {
        int4 s = ip[ch];
        unsigned int u0 = ht8[s.x * 16 + cl];
        unsigned int u1 = ht8[s.y * 16 + cl];
        unsigned int u2 = ht8[s.z * 16 + cl];
        unsigned int u3 = ht8[s.w * 16 + cl];
        a0l += fp8_lo(u0); a0h += fp8_hi(u0);
        a1l += fp8_lo(u1); a1h += fp8_hi(u1);
        a2l += fp8_lo(u2); a2h += fp8_hi(u2);
        a3l += fp8_lo(u3); a3h += fp8_hi(u3);
    }
    f32x2 al = (a0l + a1l) + (a2l + a3l);
    f32x2 ah = (a0h + a1h) + (a2h + a3h);
    float4 A = make_float4(al.x, al.y, ah.x, ah.y);
    A.x += __shfl_xor(A.x, 32); A.y += __shfl_xor(A.y, 32);
    A.z += __shfl_xor(A.z, 32); A.w += __shfl_xor(A.w, 32);
    A.x += __shfl_xor(A.x, 16); A.y += __shfl_xor(A.y, 16);
    A.z += __shfl_xor(A.z, 16); A.w += __shfl_xor(A.w, 16);
    if (grp != 0) return;
    float q = isq[node];
    float4 scv = ((const float4*)sc)[cl];
    float4 shv = ((const float4*)sh)[cl];
    A.x = fmaf(A.x * q, scv.x, shv.x);
    A.y = fmaf(A.y * q, scv.y, shv.y);
    A.z = fmaf(A.z * q, scv.z, shv.z);
    A.w = fmaf(A.w * q, scv.w, shv.w);
    if (MODE < 2) {
        A.x = fmaxf(A.x, 0.f); A.y = fmaxf(A.y, 0.f);
        A.z = fmaxf(A.z, 0.f); A.w = fmaxf(A.w, 0.f);
        if (MODE == 1) {
            uint2 r = ((const uint2*)xres)[node * 16 + cl];
            A.x += u2f(r.x << 16); A.y += u2f(r.x & 0xffff0000u);
            A.z += u2f(r.y << 16); A.w += u2f(r.y & 0xffff0000u);
        }
    }
    uint2 o;
    o.x = f2bf(A.x) | (f2bf(A.y) << 16);
    o.y = f2bf(A.z) | (f2bf(A.w) << 16);
    ((uint2*)out)[node * 16 + cl] = o;
}

// ---------------- pooling (batch sorted -> binary search), 4-row ILP, bf16 in ----------------

__device__ inline int lbound(const int* __restrict__ a, int n, int key) {
    int lo = 0, hi = n;
    while (lo < hi) {
        int mid = (lo + hi) >> 1;
        if (a[mid] < key) lo = mid + 1; else hi = mid;
    }
    return lo;
}

__global__ void k_pool(const unsigned short* __restrict__ x4, const int* __restrict__ batch,
                       float* __restrict__ pooled, int N) {
    int g = blockIdx.x;
    int c = threadIdx.x;  // 64 threads
    int lo = lbound(batch, N, g);
    int hi = lbound(batch, N, g + 1);
    float s0 = 0.f, s1 = 0.f, s2 = 0.f, s3 = 0.f;
    int i = lo;
    for (; i + 3 < hi; i += 4) {
        s0 += u2f(((unsigned int)x4[i * 64 + c]) << 16);
        s1 += u2f(((unsigned int)x4[(i + 1) * 64 + c]) << 16);
        s2 += u2f(((unsigned int)x4[(i + 2) * 64 + c]) << 16);
        s3 += u2f(((unsigned int)x4[(i + 3) * 64 + c]) << 16);
    }
    for (; i < hi; i++) s0 += u2f(((unsigned int)x4[i * 64 + c]) << 16);
    float s = (s0 + s1) + (s2 + s3);
    pooled[g * 64 + c] = s / fmaxf((float)(hi - lo), 1.0f);
}

// ---------------- MLP head + log_softmax ----------------

__global__ void k_head(const float* __restrict__ pooled, const float* __restrict__ lw1,
                       const float* __restrict__ lb1, const float* __restrict__ lw2,
                       const float* __restrict__ lb2, float* __restrict__ out, int G) {
    __shared__ float w1s[2048];
    __shared__ float w2s[64];
    int t = threadIdx.x;
    for (int i = t; i < 2048; i += 256) w1s[i] = lw1[i];
    if (t < 64) w2s[t] = lw2[t];
    __syncthreads();
    int g = blockIdx.x * 256 + t;
    if (g >= G) return;
    float p[64];
#pragma unroll
    for (int k = 0; k < 64; k++) p[k] = pooled[g * 64 + k];
    float l0 = lb2[0], l1 = lb2[1];
    for (int j = 0; j < 32; j++) {
        float hj = lb1[j];
#pragma unroll
        for (int k = 0; k < 64; k++) hj = fmaf(p[k], w1s[k * 32 + j], hj);
        hj = fmaxf(hj, 0.f);
        l0 = fmaf(hj, w2s[j * 2 + 0], l0);
        l1 = fmaf(hj, w2s[j * 2 + 1], l1);
    }
    float mx = fmaxf(l0, l1);
    float lse = mx + logf(expf(l0 - mx) + expf(l1 - mx));
    out[g * 2 + 0] = l0 - lse;
    out[g * 2 + 1] = l1 - lse;
}

// ---------------- launch ----------------

extern "C" void kernel_launch(void* const* d_in, const int* in_sizes, int n_in,
                              void* d_out, int out_size, void* d_ws, size_t ws_size,
                              hipStream_t stream) {
    const float* x   = (const float*)d_in[0];
    const float* W1  = (const float*)d_in[1];
    const float* b1  = (const float*)d_in[2];
    const float* W2  = (const float*)d_in[3];
    const float* b2  = (const float*)d_in[4];
    const float* W3  = (const float*)d_in[5];
    const float* b3  = (const float*)d_in[6];
    const float* W4  = (const float*)d_in[7];
    const float* b4  = (const float*)d_in[8];
    const float* g1  = (const float*)d_in[9];
    const float* be1 = (const float*)d_in[10];
    const float* m1  = (const float*)d_in[11];
    const float* v1  = (const float*)d_in[12];
    const float* g2  = (const float*)d_in[13];
    const float* be2 = (const float*)d_in[14];
    const float* m2  = (const float*)d_in[15];
    const float* v2  = (const float*)d_in[16];
    const float* g3  = (const float*)d_in[17];
    const float* be3 = (const float*)d_in[18];
    const float* m3  = (const float*)d_in[19];
    const float* v3  = (const float*)d_in[20];
    const float* lw1 = (const float*)d_in[21];
    const float* lb1 = (const float*)d_in[22];
    const float* lw2 = (const float*)d_in[23];
    const float* lb2 = (const float*)d_in[24];
    const int* src   = (const int*)d_in[25];
    const int* dst   = (const int*)d_in[26];
    const int* batch = (const int*)d_in[27];

    const int N = in_sizes[0] / 3;
    const int E = in_sizes[25];
    const int G = out_size / 2;

    char* w = (char*)d_ws;
    size_t off = 0;
    auto carve = [&](size_t bytes) -> void* {
        void* p = w + off;
        off = (off + bytes + 255) & ~(size_t)255;
        return p;
    };
    const int nbkt = (N + 255) >> BKT_SHIFT;
    int*   cnt     = (int*)  carve((size_t)N * 4);
    float* isq     = (float*)carve((size_t)N * 4);
    int*   rs      = (int*)  carve((size_t)N * 4);
    int*   bcur    = (int*)  carve(1024 * 4);
    float* scsh    = (float*)carve(8 * 64 * 4);
    int*   ssrc    = (int*)  carve((size_t)nbkt * SS_CAP * 4);
    unsigned int* ebuf = (unsigned int*)carve((size_t)nbkt * BKT_CAP * 4);
    unsigned int* ht = (unsigned int*)carve((size_t)(N + 1) * 64);  // fp8 rows, +1 zero row
    unsigned short* xa = (unsigned short*)carve((size_t)N * 64 * 2);  // bf16 trunk
    unsigned short* xb = (unsigned short*)carve((size_t)N * 64 * 2);
    float* pooled  = (float*)carve((size_t)G * 64 * 4);
    (void)ws_size; (void)n_in;

    const int nbNode4 = (N + 3) / 4;
    const int nbT64 = (N + 31) / 32;
    const int nbMs = (E + EPB - 1) / EPB;
    float* outp = (float*)d_out;

    // CSR build + param prefold
    k_binit<<<(nbkt + 255) / 256, 256, 0, stream>>>(bcur, nbkt);
    k_prep<<<1, 256, 0, stream>>>(b1, g1, be1, m1, v1, b2, g2, be2, m2, v2,
                                  b3, g3, be3, m3, v3, b4, scsh);
    k_mscat<<<nbMs, MS_THREADS, 0, stream>>>(src, dst, bcur, ebuf, E, nbkt);
    k_bfin<<<nbkt, 512, 0, stream>>>(ebuf, bcur, cnt, isq, rs, ssrc, N);
    hipMemsetAsync((char*)ht + (size_t)N * 64, 0, 64, stream);  // zero sentinel row

    dim3 tb(64, 4);

    // layer 1: x -> ht(fp8) -> xa(bf16)
    k_transform3<<<nbNode4, tb, 0, stream>>>(x, W1, isq, (unsigned short*)ht, N);
    k_rowwave<0><<<nbNode4, 256, 0, stream>>>(ht, rs, cnt, ssrc, isq,
                                              scsh + 0, scsh + 64, nullptr, xa, N);
    // layer 2
    k_transform64<<<nbT64, tb, 0, stream>>>(xa, W2, isq, (unsigned short*)ht, N);
    k_rowwave<1><<<nbNode4, 256, 0, stream>>>(ht, rs, cnt, ssrc, isq,
                                              scsh + 128, scsh + 192, xa, xb, N);
    // layer 3
    k_transform64<<<nbT64, tb, 0, stream>>>(xb, W3, isq, (unsigned short*)ht, N);
    k_rowwave<1><<<nbNode4, 256, 0, stream>>>(ht, rs, cnt, ssrc, isq,
                                              scsh + 256, scsh + 320, xb, xa, N);
    // layer 4
    k_transform64<<<nbT64, tb, 0, stream>>>(xa, W4, isq, (unsigned short*)ht, N);
    k_rowwave<2><<<nbNode4, 256, 0, stream>>>(ht, rs, cnt, ssrc, isq,
                                              scsh + 384, scsh + 448, nullptr, xb, N);

    // pool + head
    k_pool<<<G, 64, 0, stream>>>(xb, batch, pooled, N);
    k_head<<<(G + 255) / 256, 256, 0, stream>>>(pooled, lw1, lb1, lw2, lb2, outp, G);
}

// Round 18
// 408.524 us; speedup vs baseline: 1.1275x; 1.1275x over previous
//
#include <hip/hip_runtime.h>
#include <math.h>

#define BN_EPS 1e-5f
#define EPT 16
#define MS_THREADS 512
#define EPB (MS_THREADS * EPT)   // 8192 edges per mscat block
#define BKT_SHIFT 8              // 256 nodes per bucket
#define BKT_CAP 10240            // fixed per-bucket edge capacity (mean 8192)
#define SS_CAP 11264             // ssrc per-bucket stride (padded lists, mult of 4)

typedef float f32x2 __attribute__((ext_vector_type(2)));

// fp8 e4m3 (OCP) helpers — gfx950 HW converters
__device__ inline f32x2 fp8_lo(unsigned int u) {
    return __builtin_amdgcn_cvt_pk_f32_fp8(u, false);   // bytes 0,1 -> 2 f32
}
__device__ inline f32x2 fp8_hi(unsigned int u) {
    return __builtin_amdgcn_cvt_pk_f32_fp8(u, true);    // bytes 2,3 -> 2 f32
}
__device__ inline unsigned short pack_fp8x2(float a, float b) {
    return (unsigned short)(__builtin_amdgcn_cvt_pk_fp8_f32(a, b, 0, false) & 0xFFFFu);
}

// ---------------- CSR construction (bucketed, fixed-capacity) ----------------

__global__ void k_binit(int* __restrict__ bcur, int nbkt) {
    int i = blockIdx.x * 256 + threadIdx.x;
    if (i < nbkt) bcur[i] = i * BKT_CAP;
}

// scatter packed (src | dlo<<24) into fixed-capacity buckets; int4 edge loads.
__global__ void k_mscat(const int* __restrict__ src, const int* __restrict__ dst,
                        int* __restrict__ bcur, unsigned int* __restrict__ ebuf,
                        int E, int nbkt) {
    __shared__ int hist[512];
    __shared__ int basel[512];
    int t = threadIdx.x;  // 512
    for (int i = t; i < nbkt; i += MS_THREADS) hist[i] = 0;
    __syncthreads();
    int e0 = blockIdx.x * EPB;
    const int4* src4 = (const int4*)src;
    const int4* dst4 = (const int4*)dst;
    int es[EPT], ed[EPT];
#pragma unroll
    for (int k = 0; k < EPT / 4; k++) {
        int i4 = (e0 >> 2) + t + k * MS_THREADS;
        int ebase = i4 << 2;
        if (ebase + 3 < E) {
            int4 sv = src4[i4];
            int4 dv = dst4[i4];
            es[4 * k + 0] = sv.x; ed[4 * k + 0] = dv.x;
            es[4 * k + 1] = sv.y; ed[4 * k + 1] = dv.y;
            es[4 * k + 2] = sv.z; ed[4 * k + 2] = dv.z;
            es[4 * k + 3] = sv.w; ed[4 * k + 3] = dv.w;
        } else {
#pragma unroll
            for (int j = 0; j < 4; j++) {
                int e = ebase + j;
                if (e < E) { es[4 * k + j] = src[e]; ed[4 * k + j] = dst[e]; }
                else { es[4 * k + j] = 0; ed[4 * k + j] = -1; }
            }
        }
    }
#pragma unroll
    for (int k = 0; k < EPT; k++)
        if (ed[k] >= 0) atomicAdd(&hist[ed[k] >> BKT_SHIFT], 1);
    __syncthreads();
    for (int i = t; i < nbkt; i += MS_THREADS) {
        int h = hist[i];
        basel[i] = h ? atomicAdd(&bcur[i], h) : 0;
    }
    __syncthreads();
#pragma unroll
    for (int k = 0; k < EPT; k++) {
        if (ed[k] >= 0) {
            int bkt = ed[k] >> BKT_SHIFT;
            int pos = atomicAdd(&basel[bkt], 1);
            if (pos < (bkt + 1) * BKT_CAP)
                ebuf[pos] = (unsigned int)es[k] | ((unsigned int)(ed[k] & 255) << 24);
        }
    }
}

// per-bucket finalize: padded counts/scan, coalesced cnt/isq/rs, sentinel pads,
// place ssrc. Both ebuf passes use uint4 loads.
__global__ void k_bfin(const unsigned int* __restrict__ ebuf, const int* __restrict__ bcur,
                       int* __restrict__ cnt, float* __restrict__ isq, int* __restrict__ rs,
                       int* __restrict__ ssrc, int N) {
    __shared__ int h[256];
    __shared__ int sc[256];
    __shared__ int curl[256];
    int b = blockIdx.x;
    int t = threadIdx.x;  // 512 threads
    int base = b << 8;
    int s0 = b * BKT_CAP;
    int s0s = b * SS_CAP;
    int s1 = bcur[b];
    if (s1 > s0 + BKT_CAP) s1 = s0 + BKT_CAP;
    const uint4* eb4 = (const uint4*)ebuf;
    if (t < 256) h[t] = 0;
    __syncthreads();
    for (int i4 = (s0 >> 2) + t; (i4 << 2) < s1; i4 += 512) {
        int e = i4 << 2;
        uint4 w = eb4[i4];
        if (e + 3 < s1) {
            atomicAdd(&h[w.x >> 24], 1);
            atomicAdd(&h[w.y >> 24], 1);
            atomicAdd(&h[w.z >> 24], 1);
            atomicAdd(&h[w.w >> 24], 1);
        } else {
            if (e + 0 < s1) atomicAdd(&h[w.x >> 24], 1);
            if (e + 1 < s1) atomicAdd(&h[w.y >> 24], 1);
            if (e + 2 < s1) atomicAdd(&h[w.z >> 24], 1);
        }
    }
    __syncthreads();
    int cp = 0;
    if (t < 256) { cp = (h[t] + 3) & ~3; sc[t] = cp; }
    __syncthreads();
    int x = cp;
    for (int off = 1; off < 256; off <<= 1) {
        int y = (t < 256 && t >= off) ? sc[t - off] : 0;
        __syncthreads();
        if (t < 256) { x += y; sc[t] = x; }
        __syncthreads();
    }
    if (t < 256) {
        int node = base + t;
        if (node < N) {
            int c = h[t];
            int start = s0s + sc[t] - cp;
            cnt[node] = cp;
            isq[node] = rsqrtf((float)c + 1.0f);
            rs[node] = start;
            curl[t] = start;
            for (int p = c; p < cp; p++) ssrc[start + p] = N;
        }
    }
    __syncthreads();
    for (int i4 = (s0 >> 2) + t; (i4 << 2) < s1; i4 += 512) {
        int e = i4 << 2;
        uint4 w = eb4[i4];
        if (e + 0 < s1) { int p = atomicAdd(&curl[w.x >> 24], 1); ssrc[p] = (int)(w.x & 0x00FFFFFFu); }
        if (e + 1 < s1) { int p = atomicAdd(&curl[w.y >> 24], 1); ssrc[p] = (int)(w.y & 0x00FFFFFFu); }
        if (e + 2 < s1) { int p = atomicAdd(&curl[w.z >> 24], 1); ssrc[p] = (int)(w.z & 0x00FFFFFFu); }
        if (e + 3 < s1) { int p = atomicAdd(&curl[w.w >> 24], 1); ssrc[p] = (int)(w.w & 0x00FFFFFFu); }
    }
}

// ---------------- BN prefold: sc = g*rsqrt(v+eps), sh = (b-m)*sc + be ----------------
__global__ void k_prep(const float* b1, const float* g1, const float* be1,
                       const float* m1, const float* v1,
                       const float* b2, const float* g2, const float* be2,
                       const float* m2, const float* v2,
                       const float* b3, const float* g3, const float* be3,
                       const float* m3, const float* v3,
                       const float* b4, float* __restrict__ scsh) {
    int t = threadIdx.x;  // 256
    int layer = t >> 6, ch = t & 63;
    float sc, sh;
    if (layer == 3) { sc = 1.f; sh = b4[ch]; }
    else {
        const float* bb = layer == 0 ? b1 : layer == 1 ? b2 : b3;
        const float* gg = layer == 0 ? g1 : layer == 1 ? g2 : g3;
        const float* ee = layer == 0 ? be1 : layer == 1 ? be2 : be3;
        const float* mm = layer == 0 ? m1 : layer == 1 ? m2 : m3;
        const float* vv = layer == 0 ? v1 : layer == 1 ? v2 : v3;
        sc = gg[ch] * rsqrtf(vv[ch] + BN_EPS);
        sh = (bb[ch] - mm[ch]) * sc + ee[ch];
    }
    scsh[layer * 128 + ch] = sc;
    scsh[layer * 128 + 64 + ch] = sh;
}

// ---------------- dense transforms (pre-scaled by isq[node], fp8 output) ----------------

__global__ void k_transform3(const float* __restrict__ x, const float* __restrict__ W,
                             const float* __restrict__ isq, unsigned short* __restrict__ out,
                             int N) {
    __shared__ float Ws[192];
    __shared__ float xs[4][4];
    int c = threadIdx.x, ty = threadIdx.y;
    int t = ty * 64 + c;
    if (t < 192) Ws[t] = W[t];
    int node = blockIdx.x * 4 + ty;
    if (c < 3 && node < N) xs[ty][c] = x[node * 3 + c];
    __syncthreads();
    if (node >= N) return;
    float acc = xs[ty][0] * Ws[c] + xs[ty][1] * Ws[64 + c] + xs[ty][2] * Ws[128 + c];
    acc *= isq[node];
    float partner = __shfl_xor(acc, 1);
    if (!(c & 1)) out[node * 32 + (c >> 1)] = pack_fp8x2(acc, partner);
}

// 32 nodes per block; W transposed in LDS for b128 reads; fp8 pair-packed output.
__global__ void k_transform64(const float* __restrict__ in, const float* __restrict__ W,
                              const float* __restrict__ isq, unsigned short* __restrict__ out,
                              int N) {
    __shared__ float Wt[64 * 68];
    __shared__ float hs[32][64];
    int c = threadIdx.x, ty = threadIdx.y;  // 64 x 4
    int t = ty * 64 + c;
    for (int i = t; i < 4096; i += 256) {
        int k = i >> 6, cc = i & 63;
        Wt[cc * 68 + k] = W[i];
    }
    int base = blockIdx.x * 32;
    for (int r = ty; r < 32; r += 4) {
        int node = base + r;
        hs[r][c] = (node < N) ? in[node * 64 + c] : 0.f;
    }
    __syncthreads();
    const float4* wrow = (const float4*)&Wt[c * 68];
    for (int r = ty; r < 32; r += 4) {
        int node = base + r;
        if (node >= N) continue;
        const float4* hrow = (const float4*)&hs[r][0];
        float acc = 0.f;
#pragma unroll
        for (int k4 = 0; k4 < 16; k4++) {
            float4 wv = wrow[k4];
            float4 hv = hrow[k4];
            acc = fmaf(hv.x, wv.x, acc);
            acc = fmaf(hv.y, wv.y, acc);
            acc = fmaf(hv.z, wv.z, acc);
            acc = fmaf(hv.w, wv.w, acc);
        }
        acc *= isq[node];
        float partner = __shfl_xor(acc, 1);
        if (!(c & 1)) out[node * 32 + (c >> 1)] = pack_fp8x2(acc, partner);
    }
}

// ---------------- fused CSR aggregate + prefolded BN + ReLU + residual ----------------
// ONE NODE PER 16-LANE GROUP (4 nodes/wave): the group's 16 lanes cover the node's
// full 64B fp8 row, so no cross-group shuffle merge, no idle epilogue lanes; the
// self-loop is added by the owning group. Per iteration: 1 broadcast int4 idx load
// + 4 gathers = 5 VMEM per 16 edges (same shape as before). Lists padded to mult
// of 4 with sentinel N (zero row). MODE 0: relu; 1: relu+res; 2: plain.
template <int MODE>
__global__ void k_rowwave(const unsigned int* __restrict__ ht8, const int* __restrict__ rs,
                          const int* __restrict__ cnt, const int* __restrict__ ssrc,
                          const float* __restrict__ isq,
                          const float* __restrict__ sc, const float* __restrict__ sh,
                          const float* __restrict__ xres,
                          float* __restrict__ out, int N) {
    int tid = threadIdx.x;
    int cl = tid & 15;               // channel quad (4 fp8 = 1 dword)
    int node = (blockIdx.x << 4) + (tid >> 4);   // 16 nodes per 256-thr block
    if (node >= N) return;
    f32x2 a0l = {0.f, 0.f}, a0h = {0.f, 0.f};
    f32x2 a1l = {0.f, 0.f}, a1h = {0.f, 0.f};
    f32x2 a2l = {0.f, 0.f}, a2h = {0.f, 0.f};
    f32x2 a3l = {0.f, 0.f}, a3h = {0.f, 0.f};
    {   // self-loop (all 16 lanes of the owning group)
        unsigned int u = ht8[node * 16 + cl];
        a0l += fp8_lo(u); a0h += fp8_hi(u);
    }
    int st = rs[node];
    int nch = cnt[node] >> 2;        // int4 chunks (padded)
    const int4* ip = (const int4*)(ssrc + st);
    for (int ch = 0; ch < nch; ch++) {
        int4 s = ip[ch];             // broadcast within group
        unsigned int u0 = ht8[s.x * 16 + cl];
        unsigned int u1 = ht8[s.y * 16 + cl];
        unsigned int u2 = ht8[s.z * 16 + cl];
        unsigned int u3 = ht8[s.w * 16 + cl];
        a0l += fp8_lo(u0); a0h += fp8_hi(u0);
        a1l += fp8_lo(u1); a1h += fp8_hi(u1);
        a2l += fp8_lo(u2); a2h += fp8_hi(u2);
        a3l += fp8_lo(u3); a3h += fp8_hi(u3);
    }
    f32x2 al = (a0l + a1l) + (a2l + a3l);
    f32x2 ah = (a0h + a1h) + (a2h + a3h);
    float4 A = make_float4(al.x, al.y, ah.x, ah.y);
    float q = isq[node];
    float4 scv = ((const float4*)sc)[cl];
    float4 shv = ((const float4*)sh)[cl];
    A.x = fmaf(A.x * q, scv.x, shv.x);
    A.y = fmaf(A.y * q, scv.y, shv.y);
    A.z = fmaf(A.z * q, scv.z, shv.z);
    A.w = fmaf(A.w * q, scv.w, shv.w);
    if (MODE < 2) {
        A.x = fmaxf(A.x, 0.f); A.y = fmaxf(A.y, 0.f);
        A.z = fmaxf(A.z, 0.f); A.w = fmaxf(A.w, 0.f);
        if (MODE == 1) {
            float4 r = ((const float4*)(xres + node * 64))[cl];
            A.x += r.x; A.y += r.y; A.z += r.z; A.w += r.w;
        }
    }
    ((float4*)(out + node * 64))[cl] = A;
}

// ---------------- pooling (batch sorted -> binary search), 4-row ILP ----------------

__device__ inline int lbound(const int* __restrict__ a, int n, int key) {
    int lo = 0, hi = n;
    while (lo < hi) {
        int mid = (lo + hi) >> 1;
        if (a[mid] < key) lo = mid + 1; else hi = mid;
    }
    return lo;
}

__global__ void k_pool(const float* __restrict__ x4, const int* __restrict__ batch,
                       float* __restrict__ pooled, int N) {
    int g = blockIdx.x;
    int c = threadIdx.x;  // 64 threads
    int lo = lbound(batch, N, g);
    int hi = lbound(batch, N, g + 1);
    float s0 = 0.f, s1 = 0.f, s2 = 0.f, s3 = 0.f;
    int i = lo;
    for (; i + 3 < hi; i += 4) {
        s0 += x4[i * 64 + c];
        s1 += x4[(i + 1) * 64 + c];
        s2 += x4[(i + 2) * 64 + c];
        s3 += x4[(i + 3) * 64 + c];
    }
    for (; i < hi; i++) s0 += x4[i * 64 + c];
    float s = (s0 + s1) + (s2 + s3);
    pooled[g * 64 + c] = s / fmaxf((float)(hi - lo), 1.0f);
}

// ---------------- MLP head + log_softmax ----------------

__global__ void k_head(const float* __restrict__ pooled, const float* __restrict__ lw1,
                       const float* __restrict__ lb1, const float* __restrict__ lw2,
                       const float* __restrict__ lb2, float* __restrict__ out, int G) {
    __shared__ float w1s[2048];
    __shared__ float w2s[64];
    int t = threadIdx.x;
    for (int i = t; i < 2048; i += 256) w1s[i] = lw1[i];
    if (t < 64) w2s[t] = lw2[t];
    __syncthreads();
    int g = blockIdx.x * 256 + t;
    if (g >= G) return;
    float p[64];
#pragma unroll
    for (int k = 0; k < 64; k++) p[k] = pooled[g * 64 + k];
    float l0 = lb2[0], l1 = lb2[1];
    for (int j = 0; j < 32; j++) {
        float hj = lb1[j];
#pragma unroll
        for (int k = 0; k < 64; k++) hj = fmaf(p[k], w1s[k * 32 + j], hj);
        hj = fmaxf(hj, 0.f);
        l0 = fmaf(hj, w2s[j * 2 + 0], l0);
        l1 = fmaf(hj, w2s[j * 2 + 1], l1);
    }
    float mx = fmaxf(l0, l1);
    float lse = mx + logf(expf(l0 - mx) + expf(l1 - mx));
    out[g * 2 + 0] = l0 - lse;
    out[g * 2 + 1] = l1 - lse;
}

// ---------------- launch ----------------

extern "C" void kernel_launch(void* const* d_in, const int* in_sizes, int n_in,
                              void* d_out, int out_size, void* d_ws, size_t ws_size,
                              hipStream_t stream) {
    const float* x   = (const float*)d_in[0];
    const float* W1  = (const float*)d_in[1];
    const float* b1  = (const float*)d_in[2];
    const float* W2  = (const float*)d_in[3];
    const float* b2  = (const float*)d_in[4];
    const float* W3  = (const float*)d_in[5];
    const float* b3  = (const float*)d_in[6];
    const float* W4  = (const float*)d_in[7];
    const float* b4  = (const float*)d_in[8];
    const float* g1  = (const float*)d_in[9];
    const float* be1 = (const float*)d_in[10];
    const float* m1  = (const float*)d_in[11];
    const float* v1  = (const float*)d_in[12];
    const float* g2  = (const float*)d_in[13];
    const float* be2 = (const float*)d_in[14];
    const float* m2  = (const float*)d_in[15];
    const float* v2  = (const float*)d_in[16];
    const float* g3  = (const float*)d_in[17];
    const float* be3 = (const float*)d_in[18];
    const float* m3  = (const float*)d_in[19];
    const float* v3  = (const float*)d_in[20];
    const float* lw1 = (const float*)d_in[21];
    const float* lb1 = (const float*)d_in[22];
    const float* lw2 = (const float*)d_in[23];
    const float* lb2 = (const float*)d_in[24];
    const int* src   = (const int*)d_in[25];
    const int* dst   = (const int*)d_in[26];
    const int* batch = (const int*)d_in[27];

    const int N = in_sizes[0] / 3;
    const int E = in_sizes[25];
    const int G = out_size / 2;

    char* w = (char*)d_ws;
    size_t off = 0;
    auto carve = [&](size_t bytes) -> void* {
        void* p = w + off;
        off = (off + bytes + 255) & ~(size_t)255;
        return p;
    };
    const int nbkt = (N + 255) >> BKT_SHIFT;
    int*   cnt     = (int*)  carve((size_t)N * 4);
    float* isq     = (float*)carve((size_t)N * 4);
    int*   rs      = (int*)  carve((size_t)N * 4);
    int*   bcur    = (int*)  carve(1024 * 4);
    float* scsh    = (float*)carve(8 * 64 * 4);
    int*   ssrc    = (int*)  carve((size_t)nbkt * SS_CAP * 4);
    unsigned int* ebuf = (unsigned int*)carve((size_t)nbkt * BKT_CAP * 4);
    unsigned int* ht = (unsigned int*)carve((size_t)(N + 1) * 64);  // fp8 rows, +1 zero row
    float* xa      = (float*)carve((size_t)N * 64 * 4);
    float* xb      = (float*)carve((size_t)N * 64 * 4);
    float* pooled  = (float*)carve((size_t)G * 64 * 4);
    (void)ws_size; (void)n_in;

    const int nbNode4 = (N + 3) / 4;
    const int nbNode16 = (N + 15) / 16;
    const int nbT64 = (N + 31) / 32;
    const int nbMs = (E + EPB - 1) / EPB;
    float* outp = (float*)d_out;

    // CSR build + param prefold
    k_binit<<<(nbkt + 255) / 256, 256, 0, stream>>>(bcur, nbkt);
    k_prep<<<1, 256, 0, stream>>>(b1, g1, be1, m1, v1, b2, g2, be2, m2, v2,
                                  b3, g3, be3, m3, v3, b4, scsh);
    k_mscat<<<nbMs, MS_THREADS, 0, stream>>>(src, dst, bcur, ebuf, E, nbkt);
    k_bfin<<<nbkt, 512, 0, stream>>>(ebuf, bcur, cnt, isq, rs, ssrc, N);
    hipMemsetAsync((char*)ht + (size_t)N * 64, 0, 64, stream);  // zero sentinel row

    dim3 tb(64, 4);

    // layer 1: x -> ht(fp8) -> xa
    k_transform3<<<nbNode4, tb, 0, stream>>>(x, W1, isq, (unsigned short*)ht, N);
    k_rowwave<0><<<nbNode16, 256, 0, stream>>>(ht, rs, cnt, ssrc, isq,
                                               scsh + 0, scsh + 64, nullptr, xa, N);
    // layer 2
    k_transform64<<<nbT64, tb, 0, stream>>>(xa, W2, isq, (unsigned short*)ht, N);
    k_rowwave<1><<<nbNode16, 256, 0, stream>>>(ht, rs, cnt, ssrc, isq,
                                               scsh + 128, scsh + 192, xa, xb, N);
    // layer 3
    k_transform64<<<nbT64, tb, 0, stream>>>(xb, W3, isq, (unsigned short*)ht, N);
    k_rowwave<1><<<nbNode16, 256, 0, stream>>>(ht, rs, cnt, ssrc, isq,
                                               scsh + 256, scsh + 320, xb, xa, N);
    // layer 4
    k_transform64<<<nbT64, tb, 0, stream>>>(xa, W4, isq, (unsigned short*)ht, N);
    k_rowwave<2><<<nbNode16, 256, 0, stream>>>(ht, rs, cnt, ssrc, isq,
                                               scsh + 384, scsh + 448, nullptr, xb, N);

    // pool + head
    k_pool<<<G, 64, 0, stream>>>(xb, batch, pooled, N);
    k_head<<<(G + 255) / 256, 256, 0, stream>>>(pooled, lw1, lb1, lw2, lb2, outp, G);
}

// Round 19
// 385.753 us; speedup vs baseline: 1.1941x; 1.0590x over previous
//
#include <hip/hip_runtime.h>
#include <math.h>

#define BN_EPS 1e-5f
#define EPT 4
#define MS_THREADS 512
#define EPB (MS_THREADS * EPT)   // 2048 edges per mscat block
#define BKT_SHIFT 8              // 256 nodes per bucket
#define BKT_CAP 10240            // fixed per-bucket edge capacity (mean 8192)
#define SS_CAP 11264             // ssrc per-bucket stride (padded lists, mult of 4)

typedef float f32x2 __attribute__((ext_vector_type(2)));

// fp8 e4m3 (OCP) helpers — gfx950 HW converters
__device__ inline f32x2 fp8_lo(unsigned int u) {
    return __builtin_amdgcn_cvt_pk_f32_fp8(u, false);   // bytes 0,1 -> 2 f32
}
__device__ inline f32x2 fp8_hi(unsigned int u) {
    return __builtin_amdgcn_cvt_pk_f32_fp8(u, true);    // bytes 2,3 -> 2 f32
}
__device__ inline unsigned short pack_fp8x2(float a, float b) {
    return (unsigned short)(__builtin_amdgcn_cvt_pk_fp8_f32(a, b, 0, false) & 0xFFFFu);
}

// ---------------- init: block 0 = BN prefold; blocks 1.. = bcur init ----------------
__global__ void k_init(int* __restrict__ bcur, int nbkt,
                       const float* b1, const float* g1, const float* be1,
                       const float* m1, const float* v1,
                       const float* b2, const float* g2, const float* be2,
                       const float* m2, const float* v2,
                       const float* b3, const float* g3, const float* be3,
                       const float* m3, const float* v3,
                       const float* b4, float* __restrict__ scsh) {
    int t = threadIdx.x;  // 256
    if (blockIdx.x == 0) {
        int layer = t >> 6, ch = t & 63;
        float sc, sh;
        if (layer == 3) { sc = 1.f; sh = b4[ch]; }
        else {
            const float* bb = layer == 0 ? b1 : layer == 1 ? b2 : b3;
            const float* gg = layer == 0 ? g1 : layer == 1 ? g2 : g3;
            const float* ee = layer == 0 ? be1 : layer == 1 ? be2 : be3;
            const float* mm = layer == 0 ? m1 : layer == 1 ? m2 : m3;
            const float* vv = layer == 0 ? v1 : layer == 1 ? v2 : v3;
            sc = gg[ch] * rsqrtf(vv[ch] + BN_EPS);
            sh = (bb[ch] - mm[ch]) * sc + ee[ch];
        }
        scsh[layer * 128 + ch] = sc;
        scsh[layer * 128 + 64 + ch] = sh;
    } else {
        int i = (blockIdx.x - 1) * 256 + t;
        if (i < nbkt) bcur[i] = i * BKT_CAP;
    }
}

// scatter packed (src | dlo<<24) into fixed-capacity buckets; int4 edge loads.
__global__ void k_mscat(const int* __restrict__ src, const int* __restrict__ dst,
                        int* __restrict__ bcur, unsigned int* __restrict__ ebuf,
                        int E, int nbkt) {
    __shared__ int hist[512];
    __shared__ int basel[512];
    int t = threadIdx.x;  // 512
    for (int i = t; i < nbkt; i += MS_THREADS) hist[i] = 0;
    __syncthreads();
    int e0 = blockIdx.x * EPB;
    const int4* src4 = (const int4*)src;
    const int4* dst4 = (const int4*)dst;
    int es[EPT], ed[EPT];
#pragma unroll
    for (int k = 0; k < EPT / 4; k++) {
        int i4 = (e0 >> 2) + t + k * MS_THREADS;
        int ebase = i4 << 2;
        if (ebase + 3 < E) {
            int4 sv = src4[i4];
            int4 dv = dst4[i4];
            es[4 * k + 0] = sv.x; ed[4 * k + 0] = dv.x;
            es[4 * k + 1] = sv.y; ed[4 * k + 1] = dv.y;
            es[4 * k + 2] = sv.z; ed[4 * k + 2] = dv.z;
            es[4 * k + 3] = sv.w; ed[4 * k + 3] = dv.w;
        } else {
#pragma unroll
            for (int j = 0; j < 4; j++) {
                int e = ebase + j;
                if (e < E) { es[4 * k + j] = src[e]; ed[4 * k + j] = dst[e]; }
                else { es[4 * k + j] = 0; ed[4 * k + j] = -1; }
            }
        }
    }
#pragma unroll
    for (int k = 0; k < EPT; k++)
        if (ed[k] >= 0) atomicAdd(&hist[ed[k] >> BKT_SHIFT], 1);
    __syncthreads();
    for (int i = t; i < nbkt; i += MS_THREADS) {
        int h = hist[i];
        basel[i] = h ? atomicAdd(&bcur[i], h) : 0;
    }
    __syncthreads();
#pragma unroll
    for (int k = 0; k < EPT; k++) {
        if (ed[k] >= 0) {
            int bkt = ed[k] >> BKT_SHIFT;
            int pos = atomicAdd(&basel[bkt], 1);
            if (pos < (bkt + 1) * BKT_CAP)
                ebuf[pos] = (unsigned int)es[k] | ((unsigned int)(ed[k] & 255) << 24);
        }
    }
}

// per-bucket finalize, SINGLE global pass: stage ebuf segment in LDS while
// histogramming; scan; write cnt/isq/rs; place ssrc from the LDS copy.
__global__ void k_bfin(const unsigned int* __restrict__ ebuf, const int* __restrict__ bcur,
                       int* __restrict__ cnt, float* __restrict__ isq, int* __restrict__ rs,
                       int* __restrict__ ssrc, int N) {
    __shared__ unsigned int ebl[BKT_CAP];   // 40KB stage
    __shared__ int h[256];
    __shared__ int sc[256];
    __shared__ int curl[256];
    int b = blockIdx.x;
    int t = threadIdx.x;  // 512 threads
    int base = b << 8;
    int s0 = b * BKT_CAP;
    int s0s = b * SS_CAP;
    int s1 = bcur[b];
    if (s1 > s0 + BKT_CAP) s1 = s0 + BKT_CAP;
    int len = s1 - s0;
    const uint4* eb4 = (const uint4*)ebuf;
    if (t < 256) h[t] = 0;
    __syncthreads();
    for (int i4 = (s0 >> 2) + t; (i4 << 2) < s1; i4 += 512) {
        int e = i4 << 2;
        uint4 w = eb4[i4];
        *((uint4*)&ebl[e - s0]) = w;
        if (e + 3 < s1) {
            atomicAdd(&h[w.x >> 24], 1);
            atomicAdd(&h[w.y >> 24], 1);
            atomicAdd(&h[w.z >> 24], 1);
            atomicAdd(&h[w.w >> 24], 1);
        } else {
            if (e + 0 < s1) atomicAdd(&h[w.x >> 24], 1);
            if (e + 1 < s1) atomicAdd(&h[w.y >> 24], 1);
            if (e + 2 < s1) atomicAdd(&h[w.z >> 24], 1);
        }
    }
    __syncthreads();
    int cp = 0;
    if (t < 256) { cp = (h[t] + 3) & ~3; sc[t] = cp; }
    __syncthreads();
    int x = cp;
    for (int off = 1; off < 256; off <<= 1) {
        int y = (t < 256 && t >= off) ? sc[t - off] : 0;
        __syncthreads();
        if (t < 256) { x += y; sc[t] = x; }
        __syncthreads();
    }
    if (t < 256) {
        int node = base + t;
        if (node < N) {
            int c = h[t];
            int start = s0s + sc[t] - cp;
            cnt[node] = cp;
            isq[node] = rsqrtf((float)c + 1.0f);
            rs[node] = start;
            curl[t] = start;
            for (int p = c; p < cp; p++) ssrc[start + p] = N;
        }
    }
    __syncthreads();
    for (int i = t; i < len; i += 512) {
        unsigned int w = ebl[i];
        int pos = atomicAdd(&curl[w >> 24], 1);
        ssrc[pos] = (int)(w & 0x00FFFFFFu);
    }
}

// ---------------- dense transforms (pre-scaled by isq[node], fp8 output) ----------------

__global__ void k_transform3(const float* __restrict__ x, const float* __restrict__ W,
                             const float* __restrict__ isq, unsigned short* __restrict__ out,
                             int N) {
    __shared__ float Ws[192];
    __shared__ float xs[4][4];
    int c = threadIdx.x, ty = threadIdx.y;
    int t = ty * 64 + c;
    if (t < 192) Ws[t] = W[t];
    int node = blockIdx.x * 4 + ty;
    if (c < 3 && node < N) xs[ty][c] = x[node * 3 + c];
    __syncthreads();
    if (node >= N) return;
    float acc = xs[ty][0] * Ws[c] + xs[ty][1] * Ws[64 + c] + xs[ty][2] * Ws[128 + c];
    acc *= isq[node];
    float partner = __shfl_xor(acc, 1);
    if (!(c & 1)) out[node * 32 + (c >> 1)] = pack_fp8x2(acc, partner);
}

// 32 nodes per block; W transposed in LDS for b128 reads; fp8 pair-packed output.
__global__ void k_transform64(const float* __restrict__ in, const float* __restrict__ W,
                              const float* __restrict__ isq, unsigned short* __restrict__ out,
                              int N) {
    __shared__ float Wt[64 * 68];
    __shared__ float hs[32][64];
    int c = threadIdx.x, ty = threadIdx.y;  // 64 x 4
    int t = ty * 64 + c;
    for (int i = t; i < 4096; i += 256) {
        int k = i >> 6, cc = i & 63;
        Wt[cc * 68 + k] = W[i];
    }
    int base = blockIdx.x * 32;
    for (int r = ty; r < 32; r += 4) {
        int node = base + r;
        hs[r][c] = (node < N) ? in[node * 64 + c] : 0.f;
    }
    __syncthreads();
    const float4* wrow = (const float4*)&Wt[c * 68];
    for (int r = ty; r < 32; r += 4) {
        int node = base + r;
        if (node >= N) continue;
        const float4* hrow = (const float4*)&hs[r][0];
        float acc = 0.f;
#pragma unroll
        for (int k4 = 0; k4 < 16; k4++) {
            float4 wv = wrow[k4];
            float4 hv = hrow[k4];
            acc = fmaf(hv.x, wv.x, acc);
            acc = fmaf(hv.y, wv.y, acc);
            acc = fmaf(hv.z, wv.z, acc);
            acc = fmaf(hv.w, wv.w, acc);
        }
        acc *= isq[node];
        float partner = __shfl_xor(acc, 1);
        if (!(c & 1)) out[node * 32 + (c >> 1)] = pack_fp8x2(acc, partner);
    }
}

// ---------------- fused CSR aggregate + prefolded BN + ReLU + residual ----------------
// One node per 16-lane group (4 nodes/wave). MODE 0: relu; 1: relu+res; 2: plain.
template <int MODE>
__global__ void k_rowwave(const unsigned int* __restrict__ ht8, const int* __restrict__ rs,
                          const int* __restrict__ cnt, const int* __restrict__ ssrc,
                          const float* __restrict__ isq,
                          const float* __restrict__ sc, const float* __restrict__ sh,
                          const float* __restrict__ xres,
                          float* __restrict__ out, int N) {
    int tid = threadIdx.x;
    int cl = tid & 15;               // channel quad (4 fp8 = 1 dword)
    int node = (blockIdx.x << 4) + (tid >> 4);   // 16 nodes per 256-thr block
    if (node >= N) return;
    f32x2 a0l = {0.f, 0.f}, a0h = {0.f, 0.f};
    f32x2 a1l = {0.f, 0.f}, a1h = {0.f, 0.f};
    f32x2 a2l = {0.f, 0.f}, a2h = {0.f, 0.f};
    f32x2 a3l = {0.f, 0.f}, a3h = {0.f, 0.f};
    {   // self-loop
        unsigned int u = ht8[node * 16 + cl];
        a0l += fp8_lo(u); a0h += fp8_hi(u);
    }
    int st = rs[node];
    int nch = cnt[node] >> 2;        // int4 chunks (padded)
    const int4* ip = (const int4*)(ssrc + st);
    for (int ch = 0; ch < nch; ch++) {
        int4 s = ip[ch];             // broadcast within group
        unsigned int u0 = ht8[s.x * 16 + cl];
        unsigned int u1 = ht8[s.y * 16 + cl];
        unsigned int u2 = ht8[s.z * 16 + cl];
        unsigned int u3 = ht8[s.w * 16 + cl];
        a0l += fp8_lo(u0); a0h += fp8_hi(u0);
        a1l += fp8_lo(u1); a1h += fp8_hi(u1);
        a2l += fp8_lo(u2); a2h += fp8_hi(u2);
        a3l += fp8_lo(u3); a3h += fp8_hi(u3);
    }
    f32x2 al = (a0l + a1l) + (a2l + a3l);
    f32x2 ah = (a0h + a1h) + (a2h + a3h);
    float4 A = make_float4(al.x, al.y, ah.x, ah.y);
    float q = isq[node];
    float4 scv = ((const float4*)sc)[cl];
    float4 shv = ((const float4*)sh)[cl];
    A.x = fmaf(A.x * q, scv.x, shv.x);
    A.y = fmaf(A.y * q, scv.y, shv.y);
    A.z = fmaf(A.z * q, scv.z, shv.z);
    A.w = fmaf(A.w * q, scv.w, shv.w);
    if (MODE < 2) {
        A.x = fmaxf(A.x, 0.f); A.y = fmaxf(A.y, 0.f);
        A.z = fmaxf(A.z, 0.f); A.w = fmaxf(A.w, 0.f);
        if (MODE == 1) {
            float4 r = ((const float4*)(xres + node * 64))[cl];
            A.x += r.x; A.y += r.y; A.z += r.z; A.w += r.w;
        }
    }
    ((float4*)(out + node * 64))[cl] = A;
}

// ---------------- fused pool + MLP head + log_softmax (one block per graph) ----------------

__device__ inline int lbound(const int* __restrict__ a, int n, int key) {
    int lo = 0, hi = n;
    while (lo < hi) {
        int mid = (lo + hi) >> 1;
        if (a[mid] < key) lo = mid + 1; else hi = mid;
    }
    return lo;
}

__global__ void k_poolhead(const float* __restrict__ x4, const int* __restrict__ batch,
                           const float* __restrict__ lw1, const float* __restrict__ lb1,
                           const float* __restrict__ lw2, const float* __restrict__ lb2,
                           float* __restrict__ out, int N) {
    __shared__ float w1s[2048];
    __shared__ float ps[64];
    int g = blockIdx.x;
    int c = threadIdx.x;  // 64 threads
    for (int i = c; i < 2048; i += 64) w1s[i] = lw1[i];
    int lo = lbound(batch, N, g);
    int hi = lbound(batch, N, g + 1);
    float s0 = 0.f, s1 = 0.f, s2 = 0.f, s3 = 0.f;
    int i = lo;
    for (; i + 3 < hi; i += 4) {
        s0 += x4[i * 64 + c];
        s1 += x4[(i + 1) * 64 + c];
        s2 += x4[(i + 2) * 64 + c];
        s3 += x4[(i + 3) * 64 + c];
    }
    for (; i < hi; i++) s0 += x4[i * 64 + c];
    ps[c] = ((s0 + s1) + (s2 + s3)) / fmaxf((float)(hi - lo), 1.0f);
    __syncthreads();
    float l0 = 0.f, l1 = 0.f;
    if (c < 32) {
        float hj = lb1[c];
#pragma unroll
        for (int k = 0; k < 64; k++) hj = fmaf(ps[k], w1s[k * 32 + c], hj);
        hj = fmaxf(hj, 0.f);
        l0 = hj * lw2[c * 2 + 0];
        l1 = hj * lw2[c * 2 + 1];
    }
#pragma unroll
    for (int off = 16; off >= 1; off >>= 1) {
        l0 += __shfl_down(l0, off);
        l1 += __shfl_down(l1, off);
    }
    if (c == 0) {
        l0 += lb2[0]; l1 += lb2[1];
        float mx = fmaxf(l0, l1);
        float lse = mx + logf(expf(l0 - mx) + expf(l1 - mx));
        out[g * 2 + 0] = l0 - lse;
        out[g * 2 + 1] = l1 - lse;
    }
}

// ---------------- launch ----------------

extern "C" void kernel_launch(void* const* d_in, const int* in_sizes, int n_in,
                              void* d_out, int out_size, void* d_ws, size_t ws_size,
                              hipStream_t stream) {
    const float* x   = (const float*)d_in[0];
    const float* W1  = (const float*)d_in[1];
    const float* b1  = (const float*)d_in[2];
    const float* W2  = (const float*)d_in[3];
    const float* b2  = (const float*)d_in[4];
    const float* W3  = (const float*)d_in[5];
    const float* b3  = (const float*)d_in[6];
    const float* W4  = (const float*)d_in[7];
    const float* b4  = (const float*)d_in[8];
    const float* g1  = (const float*)d_in[9];
    const float* be1 = (const float*)d_in[10];
    const float* m1  = (const float*)d_in[11];
    const float* v1  = (const float*)d_in[12];
    const float* g2  = (const float*)d_in[13];
    const float* be2 = (const float*)d_in[14];
    const float* m2  = (const float*)d_in[15];
    const float* v2  = (const float*)d_in[16];
    const float* g3  = (const float*)d_in[17];
    const float* be3 = (const float*)d_in[18];
    const float* m3  = (const float*)d_in[19];
    const float* v3  = (const float*)d_in[20];
    const float* lw1 = (const float*)d_in[21];
    const float* lb1 = (const float*)d_in[22];
    const float* lw2 = (const float*)d_in[23];
    const float* lb2 = (const float*)d_in[24];
    const int* src   = (const int*)d_in[25];
    const int* dst   = (const int*)d_in[26];
    const int* batch = (const int*)d_in[27];

    const int N = in_sizes[0] / 3;
    const int E = in_sizes[25];
    const int G = out_size / 2;

    char* w = (char*)d_ws;
    size_t off = 0;
    auto carve = [&](size_t bytes) -> void* {
        void* p = w + off;
        off = (off + bytes + 255) & ~(size_t)255;
        return p;
    };
    const int nbkt = (N + 255) >> BKT_SHIFT;
    int*   cnt     = (int*)  carve((size_t)N * 4);
    float* isq     = (float*)carve((size_t)N * 4);
    int*   rs      = (int*)  carve((size_t)N * 4);
    int*   bcur    = (int*)  carve(1024 * 4);
    float* scsh    = (float*)carve(8 * 64 * 4);
    int*   ssrc    = (int*)  carve((size_t)nbkt * SS_CAP * 4);
    unsigned int* ebuf = (unsigned int*)carve((size_t)nbkt * BKT_CAP * 4);
    unsigned int* ht = (unsigned int*)carve((size_t)(N + 1) * 64);  // fp8 rows, +1 zero row
    float* xa      = (float*)carve((size_t)N * 64 * 4);
    float* xb      = (float*)carve((size_t)N * 64 * 4);
    (void)ws_size; (void)n_in;

    const int nbNode4 = (N + 3) / 4;
    const int nbNode16 = (N + 15) / 16;
    const int nbT64 = (N + 31) / 32;
    const int nbMs = (E + EPB - 1) / EPB;
    float* outp = (float*)d_out;

    // init (prefold + bcur) + bucket build
    k_init<<<1 + (nbkt + 255) / 256, 256, 0, stream>>>(bcur, nbkt,
                                  b1, g1, be1, m1, v1, b2, g2, be2, m2, v2,
                                  b3, g3, be3, m3, v3, b4, scsh);
    k_mscat<<<nbMs, MS_THREADS, 0, stream>>>(src, dst, bcur, ebuf, E, nbkt);
    k_bfin<<<nbkt, 512, 0, stream>>>(ebuf, bcur, cnt, isq, rs, ssrc, N);
    hipMemsetAsync((char*)ht + (size_t)N * 64, 0, 64, stream);  // zero sentinel row

    dim3 tb(64, 4);

    // layer 1: x -> ht(fp8) -> xa
    k_transform3<<<nbNode4, tb, 0, stream>>>(x, W1, isq, (unsigned short*)ht, N);
    k_rowwave<0><<<nbNode16, 256, 0, stream>>>(ht, rs, cnt, ssrc, isq,
                                               scsh + 0, scsh + 64, nullptr, xa, N);
    // layer 2
    k_transform64<<<nbT64, tb, 0, stream>>>(xa, W2, isq, (unsigned short*)ht, N);
    k_rowwave<1><<<nbNode16, 256, 0, stream>>>(ht, rs, cnt, ssrc, isq,
                                               scsh + 128, scsh + 192, xa, xb, N);
    // layer 3
    k_transform64<<<nbT64, tb, 0, stream>>>(xb, W3, isq, (unsigned short*)ht, N);
    k_rowwave<1><<<nbNode16, 256, 0, stream>>>(ht, rs, cnt, ssrc, isq,
                                               scsh + 256, scsh + 320, xb, xa, N);
    // layer 4
    k_transform64<<<nbT64, tb, 0, stream>>>(xa, W4, isq, (unsigned short*)ht, N);
    k_rowwave<2><<<nbNode16, 256, 0, stream>>>(ht, rs, cnt, ssrc, isq,
                                               scsh + 384, scsh + 448, nullptr, xb, N);

    // fused pool + head
    k_poolhead<<<G, 64, 0, stream>>>(xb, batch, lw1, lb1, lw2, lb2, outp, N);
}

// Round 20
// 329.259 us; speedup vs baseline: 1.3989x; 1.1716x over previous
//
#include <hip/hip_runtime.h>
#include <math.h>

#define BN_EPS 1e-5f
#define EPT 4
#define MS_THREADS 512
#define EPB (MS_THREADS * EPT)   // 2048 edges per mscat block
#define BKT_SHIFT 8              // 256 nodes per bucket
#define BKT_CAP 10240            // fixed per-bucket edge capacity (mean 8192)
#define SS_CAP 11264             // ssrc per-bucket stride (padded lists, mult of 4)

typedef float f32x2 __attribute__((ext_vector_type(2)));

// fp8 e4m3 (OCP) helpers — gfx950 HW converters
__device__ inline f32x2 fp8_lo(unsigned int u) {
    return __builtin_amdgcn_cvt_pk_f32_fp8(u, false);   // bytes 0,1 -> 2 f32
}
__device__ inline f32x2 fp8_hi(unsigned int u) {
    return __builtin_amdgcn_cvt_pk_f32_fp8(u, true);    // bytes 2,3 -> 2 f32
}
__device__ inline unsigned int pack_fp8x2(float a, float b) {
    return __builtin_amdgcn_cvt_pk_fp8_f32(a, b, 0, false) & 0xFFFFu;
}

// ---------------- init: prefold + bcur init + ht sentinel rows ----------------
__global__ void k_init(int* __restrict__ bcur, int nbkt,
                       const float* b1, const float* g1, const float* be1,
                       const float* m1, const float* v1,
                       const float* b2, const float* g2, const float* be2,
                       const float* m2, const float* v2,
                       const float* b3, const float* g3, const float* be3,
                       const float* m3, const float* v3,
                       const float* b4, float* __restrict__ scsh,
                       unsigned int* __restrict__ hta_z, unsigned int* __restrict__ htb_z) {
    int t = threadIdx.x;  // 256
    if (blockIdx.x == 0) {
        int layer = t >> 6, ch = t & 63;
        float sc, sh;
        if (layer == 3) { sc = 1.f; sh = b4[ch]; }
        else {
            const float* bb = layer == 0 ? b1 : layer == 1 ? b2 : b3;
            const float* gg = layer == 0 ? g1 : layer == 1 ? g2 : g3;
            const float* ee = layer == 0 ? be1 : layer == 1 ? be2 : be3;
            const float* mm = layer == 0 ? m1 : layer == 1 ? m2 : m3;
            const float* vv = layer == 0 ? v1 : layer == 1 ? v2 : v3;
            sc = gg[ch] * rsqrtf(vv[ch] + BN_EPS);
            sh = (bb[ch] - mm[ch]) * sc + ee[ch];
        }
        scsh[layer * 128 + ch] = sc;
        scsh[layer * 128 + 64 + ch] = sh;
        if (t < 16) hta_z[t] = 0u;               // zero sentinel rows (16 dwords each)
        else if (t < 32) htb_z[t - 16] = 0u;
    } else {
        int i = (blockIdx.x - 1) * 256 + t;
        if (i < nbkt) bcur[i] = i * BKT_CAP;
    }
}

// scatter packed (src | dlo<<24) into fixed-capacity buckets; int4 edge loads.
__global__ void k_mscat(const int* __restrict__ src, const int* __restrict__ dst,
                        int* __restrict__ bcur, unsigned int* __restrict__ ebuf,
                        int E, int nbkt) {
    __shared__ int hist[512];
    __shared__ int basel[512];
    int t = threadIdx.x;  // 512
    for (int i = t; i < nbkt; i += MS_THREADS) hist[i] = 0;
    __syncthreads();
    int e0 = blockIdx.x * EPB;
    const int4* src4 = (const int4*)src;
    const int4* dst4 = (const int4*)dst;
    int es[EPT], ed[EPT];
#pragma unroll
    for (int k = 0; k < EPT / 4; k++) {
        int i4 = (e0 >> 2) + t + k * MS_THREADS;
        int ebase = i4 << 2;
        if (ebase + 3 < E) {
            int4 sv = src4[i4];
            int4 dv = dst4[i4];
            es[4 * k + 0] = sv.x; ed[4 * k + 0] = dv.x;
            es[4 * k + 1] = sv.y; ed[4 * k + 1] = dv.y;
            es[4 * k + 2] = sv.z; ed[4 * k + 2] = dv.z;
            es[4 * k + 3] = sv.w; ed[4 * k + 3] = dv.w;
        } else {
#pragma unroll
            for (int j = 0; j < 4; j++) {
                int e = ebase + j;
                if (e < E) { es[4 * k + j] = src[e]; ed[4 * k + j] = dst[e]; }
                else { es[4 * k + j] = 0; ed[4 * k + j] = -1; }
            }
        }
    }
#pragma unroll
    for (int k = 0; k < EPT; k++)
        if (ed[k] >= 0) atomicAdd(&hist[ed[k] >> BKT_SHIFT], 1);
    __syncthreads();
    for (int i = t; i < nbkt; i += MS_THREADS) {
        int h = hist[i];
        basel[i] = h ? atomicAdd(&bcur[i], h) : 0;
    }
    __syncthreads();
#pragma unroll
    for (int k = 0; k < EPT; k++) {
        if (ed[k] >= 0) {
            int bkt = ed[k] >> BKT_SHIFT;
            int pos = atomicAdd(&basel[bkt], 1);
            if (pos < (bkt + 1) * BKT_CAP)
                ebuf[pos] = (unsigned int)es[k] | ((unsigned int)(ed[k] & 255) << 24);
        }
    }
}

// per-bucket finalize, single global pass: stage ebuf segment in LDS while
// histogramming; scan; write cnt/isq/rs; place ssrc from the LDS copy.
__global__ void k_bfin(const unsigned int* __restrict__ ebuf, const int* __restrict__ bcur,
                       int* __restrict__ cnt, float* __restrict__ isq, int* __restrict__ rs,
                       int* __restrict__ ssrc, int N) {
    __shared__ unsigned int ebl[BKT_CAP];   // 40KB stage
    __shared__ int h[256];
    __shared__ int sc[256];
    __shared__ int curl[256];
    int b = blockIdx.x;
    int t = threadIdx.x;  // 512 threads
    int base = b << 8;
    int s0 = b * BKT_CAP;
    int s0s = b * SS_CAP;
    int s1 = bcur[b];
    if (s1 > s0 + BKT_CAP) s1 = s0 + BKT_CAP;
    int len = s1 - s0;
    const uint4* eb4 = (const uint4*)ebuf;
    if (t < 256) h[t] = 0;
    __syncthreads();
    for (int i4 = (s0 >> 2) + t; (i4 << 2) < s1; i4 += 512) {
        int e = i4 << 2;
        uint4 w = eb4[i4];
        *((uint4*)&ebl[e - s0]) = w;
        if (e + 3 < s1) {
            atomicAdd(&h[w.x >> 24], 1);
            atomicAdd(&h[w.y >> 24], 1);
            atomicAdd(&h[w.z >> 24], 1);
            atomicAdd(&h[w.w >> 24], 1);
        } else {
            if (e + 0 < s1) atomicAdd(&h[w.x >> 24], 1);
            if (e + 1 < s1) atomicAdd(&h[w.y >> 24], 1);
            if (e + 2 < s1) atomicAdd(&h[w.z >> 24], 1);
        }
    }
    __syncthreads();
    int cp = 0;
    if (t < 256) { cp = (h[t] + 3) & ~3; sc[t] = cp; }
    __syncthreads();
    int x = cp;
    for (int off = 1; off < 256; off <<= 1) {
        int y = (t < 256 && t >= off) ? sc[t - off] : 0;
        __syncthreads();
        if (t < 256) { x += y; sc[t] = x; }
        __syncthreads();
    }
    if (t < 256) {
        int node = base + t;
        if (node < N) {
            int c = h[t];
            int start = s0s + sc[t] - cp;
            cnt[node] = cp;
            isq[node] = rsqrtf((float)c + 1.0f);
            rs[node] = start;
            curl[t] = start;
            for (int p = c; p < cp; p++) ssrc[start + p] = N;
        }
    }
    __syncthreads();
    for (int i = t; i < len; i += 512) {
        unsigned int w = ebl[i];
        int pos = atomicAdd(&curl[w >> 24], 1);
        ssrc[pos] = (int)(w & 0x00FFFFFFu);
    }
}

// ---------------- dense transform for layer 1 (x[N,3] @ W1, fp8 out) ----------------

__global__ void k_transform3(const float* __restrict__ x, const float* __restrict__ W,
                             const float* __restrict__ isq, unsigned short* __restrict__ out,
                             int N) {
    __shared__ float Ws[192];
    __shared__ float xs[4][4];
    int c = threadIdx.x, ty = threadIdx.y;
    int t = ty * 64 + c;
    if (t < 192) Ws[t] = W[t];
    int node = blockIdx.x * 4 + ty;
    if (c < 3 && node < N) xs[ty][c] = x[node * 3 + c];
    __syncthreads();
    if (node >= N) return;
    float acc = xs[ty][0] * Ws[c] + xs[ty][1] * Ws[64 + c] + xs[ty][2] * Ws[128 + c];
    acc *= isq[node];
    float partner = __shfl_xor(acc, 1);
    if (!(c & 1)) out[node * 32 + (c >> 1)] = (unsigned short)pack_fp8x2(acc, partner);
}

// ---------------- fused aggregate + BN/ReLU/residual [+ next-layer transform] ----------
// One node per 16-lane group (16 nodes / 256-thr block). If FUSET: after the
// epilogue, the block computes ht_next = fp8(isq * x @ Wn) from LDS (replaces
// the standalone transform64 kernel and its trunk re-read).
// MODE 0: relu; 1: relu+res; 2: plain.
template <int MODE, bool FUSET>
__global__ void k_rowwave(const unsigned int* __restrict__ ht8, const int* __restrict__ rs,
                          const int* __restrict__ cnt, const int* __restrict__ ssrc,
                          const float* __restrict__ isq,
                          const float* __restrict__ sc, const float* __restrict__ sh,
                          const float* __restrict__ xres,
                          float* __restrict__ out,
                          const float* __restrict__ Wn, unsigned int* __restrict__ htn,
                          int N) {
    __shared__ float Ws[FUSET ? 4096 : 1];
    __shared__ float hs[FUSET ? 16 : 1][64];
    int tid = threadIdx.x;
    int cl = tid & 15;               // channel quad (4 fp8 = 1 dword)
    int nl = tid >> 4;
    int node = (blockIdx.x << 4) + nl;
    bool valid = node < N;
    if (FUSET) {
        for (int i = tid; i < 4096; i += 256) Ws[i] = Wn[i];
    }
    float4 A = make_float4(0.f, 0.f, 0.f, 0.f);
    float q = 0.f;
    if (valid) {
        f32x2 a0l = {0.f, 0.f}, a0h = {0.f, 0.f};
        f32x2 a1l = {0.f, 0.f}, a1h = {0.f, 0.f};
        f32x2 a2l = {0.f, 0.f}, a2h = {0.f, 0.f};
        f32x2 a3l = {0.f, 0.f}, a3h = {0.f, 0.f};
        {   // self-loop
            unsigned int u = ht8[node * 16 + cl];
            a0l += fp8_lo(u); a0h += fp8_hi(u);
        }
        int st = rs[node];
        int nch = cnt[node] >> 2;        // int4 chunks (padded)
        const int4* ip = (const int4*)(ssrc + st);
        for (int ch = 0; ch < nch; ch++) {
            int4 s = ip[ch];             // broadcast within group
            unsigned int u0 = ht8[s.x * 16 + cl];
            unsigned int u1 = ht8[s.y * 16 + cl];
            unsigned int u2 = ht8[s.z * 16 + cl];
            unsigned int u3 = ht8[s.w * 16 + cl];
            a0l += fp8_lo(u0); a0h += fp8_hi(u0);
            a1l += fp8_lo(u1); a1h += fp8_hi(u1);
            a2l += fp8_lo(u2); a2h += fp8_hi(u2);
            a3l += fp8_lo(u3); a3h += fp8_hi(u3);
        }
        f32x2 al = (a0l + a1l) + (a2l + a3l);
        f32x2 ah = (a0h + a1h) + (a2h + a3h);
        A = make_float4(al.x, al.y, ah.x, ah.y);
        q = isq[node];
        float4 scv = ((const float4*)sc)[cl];
        float4 shv = ((const float4*)sh)[cl];
        A.x = fmaf(A.x * q, scv.x, shv.x);
        A.y = fmaf(A.y * q, scv.y, shv.y);
        A.z = fmaf(A.z * q, scv.z, shv.z);
        A.w = fmaf(A.w * q, scv.w, shv.w);
        if (MODE < 2) {
            A.x = fmaxf(A.x, 0.f); A.y = fmaxf(A.y, 0.f);
            A.z = fmaxf(A.z, 0.f); A.w = fmaxf(A.w, 0.f);
            if (MODE == 1) {
                float4 r = ((const float4*)(xres + node * 64))[cl];
                A.x += r.x; A.y += r.y; A.z += r.z; A.w += r.w;
            }
        }
        ((float4*)(out + node * 64))[cl] = A;
    }
    if (FUSET) {
        ((float4*)&hs[nl][0])[cl] = A;   // zeros for invalid nodes
        __syncthreads();
        if (valid) {
            const float4* hrow = (const float4*)&hs[nl][0];
            float4 acc = make_float4(0.f, 0.f, 0.f, 0.f);
#pragma unroll
            for (int k4 = 0; k4 < 16; k4++) {
                float4 hv = hrow[k4];
                float4 w0 = ((const float4*)&Ws[(4 * k4 + 0) * 64])[cl];
                float4 w1 = ((const float4*)&Ws[(4 * k4 + 1) * 64])[cl];
                float4 w2 = ((const float4*)&Ws[(4 * k4 + 2) * 64])[cl];
                float4 w3 = ((const float4*)&Ws[(4 * k4 + 3) * 64])[cl];
                acc.x = fmaf(hv.x, w0.x, acc.x); acc.y = fmaf(hv.x, w0.y, acc.y);
                acc.z = fmaf(hv.x, w0.z, acc.z); acc.w = fmaf(hv.x, w0.w, acc.w);
                acc.x = fmaf(hv.y, w1.x, acc.x); acc.y = fmaf(hv.y, w1.y, acc.y);
                acc.z = fmaf(hv.y, w1.z, acc.z); acc.w = fmaf(hv.y, w1.w, acc.w);
                acc.x = fmaf(hv.z, w2.x, acc.x); acc.y = fmaf(hv.z, w2.y, acc.y);
                acc.z = fmaf(hv.z, w2.z, acc.z); acc.w = fmaf(hv.z, w2.w, acc.w);
                acc.x = fmaf(hv.w, w3.x, acc.x); acc.y = fmaf(hv.w, w3.y, acc.y);
                acc.z = fmaf(hv.w, w3.z, acc.z); acc.w = fmaf(hv.w, w3.w, acc.w);
            }
            acc.x *= q; acc.y *= q; acc.z *= q; acc.w *= q;
            unsigned int lo = pack_fp8x2(acc.x, acc.y);
            unsigned int hi = pack_fp8x2(acc.z, acc.w);
            htn[node * 16 + cl] = lo | (hi << 16);
        }
    }
}

// ---------------- fused pool + MLP head + log_softmax (one block per graph) ----------------

__device__ inline int lbound(const int* __restrict__ a, int n, int key) {
    int lo = 0, hi = n;
    while (lo < hi) {
        int mid = (lo + hi) >> 1;
        if (a[mid] < key) lo = mid + 1; else hi = mid;
    }
    return lo;
}

__global__ void k_poolhead(const float* __restrict__ x4, const int* __restrict__ batch,
                           const float* __restrict__ lw1, const float* __restrict__ lb1,
                           const float* __restrict__ lw2, const float* __restrict__ lb2,
                           float* __restrict__ out, int N) {
    __shared__ float w1s[2048];
    __shared__ float ps[64];
    int g = blockIdx.x;
    int c = threadIdx.x;  // 64 threads
    for (int i = c; i < 2048; i += 64) w1s[i] = lw1[i];
    int lo = lbound(batch, N, g);
    int hi = lbound(batch, N, g + 1);
    float s0 = 0.f, s1 = 0.f, s2 = 0.f, s3 = 0.f;
    int i = lo;
    for (; i + 3 < hi; i += 4) {
        s0 += x4[i * 64 + c];
        s1 += x4[(i + 1) * 64 + c];
        s2 += x4[(i + 2) * 64 + c];
        s3 += x4[(i + 3) * 64 + c];
    }
    for (; i < hi; i++) s0 += x4[i * 64 + c];
    ps[c] = ((s0 + s1) + (s2 + s3)) / fmaxf((float)(hi - lo), 1.0f);
    __syncthreads();
    float l0 = 0.f, l1 = 0.f;
    if (c < 32) {
        float hj = lb1[c];
#pragma unroll
        for (int k = 0; k < 64; k++) hj = fmaf(ps[k], w1s[k * 32 + c], hj);
        hj = fmaxf(hj, 0.f);
        l0 = hj * lw2[c * 2 + 0];
        l1 = hj * lw2[c * 2 + 1];
    }
#pragma unroll
    for (int off = 16; off >= 1; off >>= 1) {
        l0 += __shfl_down(l0, off);
        l1 += __shfl_down(l1, off);
    }
    if (c == 0) {
        l0 += lb2[0]; l1 += lb2[1];
        float mx = fmaxf(l0, l1);
        float lse = mx + logf(expf(l0 - mx) + expf(l1 - mx));
        out[g * 2 + 0] = l0 - lse;
        out[g * 2 + 1] = l1 - lse;
    }
}

// ---------------- launch ----------------

extern "C" void kernel_launch(void* const* d_in, const int* in_sizes, int n_in,
                              void* d_out, int out_size, void* d_ws, size_t ws_size,
                              hipStream_t stream) {
    const float* x   = (const float*)d_in[0];
    const float* W1  = (const float*)d_in[1];
    const float* b1  = (const float*)d_in[2];
    const float* W2  = (const float*)d_in[3];
    const float* b2  = (const float*)d_in[4];
    const float* W3  = (const float*)d_in[5];
    const float* b3  = (const float*)d_in[6];
    const float* W4  = (const float*)d_in[7];
    const float* b4  = (const float*)d_in[8];
    const float* g1  = (const float*)d_in[9];
    const float* be1 = (const float*)d_in[10];
    const float* m1  = (const float*)d_in[11];
    const float* v1  = (const float*)d_in[12];
    const float* g2  = (const float*)d_in[13];
    const float* be2 = (const float*)d_in[14];
    const float* m2  = (const float*)d_in[15];
    const float* v2  = (const float*)d_in[16];
    const float* g3  = (const float*)d_in[17];
    const float* be3 = (const float*)d_in[18];
    const float* m3  = (const float*)d_in[19];
    const float* v3  = (const float*)d_in[20];
    const float* lw1 = (const float*)d_in[21];
    const float* lb1 = (const float*)d_in[22];
    const float* lw2 = (const float*)d_in[23];
    const float* lb2 = (const float*)d_in[24];
    const int* src   = (const int*)d_in[25];
    const int* dst   = (const int*)d_in[26];
    const int* batch = (const int*)d_in[27];

    const int N = in_sizes[0] / 3;
    const int E = in_sizes[25];
    const int G = out_size / 2;

    char* w = (char*)d_ws;
    size_t off = 0;
    auto carve = [&](size_t bytes) -> void* {
        void* p = w + off;
        off = (off + bytes + 255) & ~(size_t)255;
        return p;
    };
    const int nbkt = (N + 255) >> BKT_SHIFT;
    int*   cnt     = (int*)  carve((size_t)N * 4);
    float* isq     = (float*)carve((size_t)N * 4);
    int*   rs      = (int*)  carve((size_t)N * 4);
    int*   bcur    = (int*)  carve(1024 * 4);
    float* scsh    = (float*)carve(8 * 64 * 4);
    int*   ssrc    = (int*)  carve((size_t)nbkt * SS_CAP * 4);
    unsigned int* ebuf = (unsigned int*)carve((size_t)nbkt * BKT_CAP * 4);
    unsigned int* hta = (unsigned int*)carve((size_t)(N + 1) * 64);  // fp8 rows + zero row
    unsigned int* htb = (unsigned int*)carve((size_t)(N + 1) * 64);
    float* xa      = (float*)carve((size_t)N * 64 * 4);
    float* xb      = (float*)carve((size_t)N * 64 * 4);
    (void)ws_size; (void)n_in;

    const int nbNode4 = (N + 3) / 4;
    const int nbNode16 = (N + 15) / 16;
    const int nbMs = (E + EPB - 1) / EPB;
    float* outp = (float*)d_out;

    // init (prefold + bcur + ht sentinels) + bucket build
    k_init<<<1 + (nbkt + 255) / 256, 256, 0, stream>>>(bcur, nbkt,
                                  b1, g1, be1, m1, v1, b2, g2, be2, m2, v2,
                                  b3, g3, be3, m3, v3, b4, scsh,
                                  hta + (size_t)N * 16, htb + (size_t)N * 16);
    k_mscat<<<nbMs, MS_THREADS, 0, stream>>>(src, dst, bcur, ebuf, E, nbkt);
    k_bfin<<<nbkt, 512, 0, stream>>>(ebuf, bcur, cnt, isq, rs, ssrc, N);

    dim3 tb(64, 4);

    // layer 1: x -> hta(fp8); rowwave1 -> xa + htb (= fp8(isq * xa @ W2))
    k_transform3<<<nbNode4, tb, 0, stream>>>(x, W1, isq, (unsigned short*)hta, N);
    k_rowwave<0, true><<<nbNode16, 256, 0, stream>>>(hta, rs, cnt, ssrc, isq,
                                               scsh + 0, scsh + 64, nullptr, xa, W2, htb, N);
    // layer 2: rowwave2 -> xb (+res xa) + hta (= fp8(isq * xb @ W3))
    k_rowwave<1, true><<<nbNode16, 256, 0, stream>>>(htb, rs, cnt, ssrc, isq,
                                               scsh + 128, scsh + 192, xa, xb, W3, hta, N);
    // layer 3: rowwave3 -> xa (+res xb) + htb (= fp8(isq * xa @ W4))
    k_rowwave<1, true><<<nbNode16, 256, 0, stream>>>(hta, rs, cnt, ssrc, isq,
                                               scsh + 256, scsh + 320, xb, xa, W4, htb, N);
    // layer 4: rowwave4 -> xb (plain)
    k_rowwave<2, false><<<nbNode16, 256, 0, stream>>>(htb, rs, cnt, ssrc, isq,
                                               scsh + 384, scsh + 448, nullptr, xb,
                                               nullptr, nullptr, N);

    // fused pool + head
    k_poolhead<<<G, 64, 0, stream>>>(xb, batch, lw1, lb1, lw2, lb2, outp, N);
}

// Round 21
// 317.070 us; speedup vs baseline: 1.4527x; 1.0384x over previous
//
#include <hip/hip_runtime.h>
#include <math.h>

#define BN_EPS 1e-5f
#define EPT 4
#define MS_THREADS 512
#define EPB (MS_THREADS * EPT)   // 2048 edges per mscat block
#define BKT_SHIFT 8              // 256 nodes per bucket
#define BKT_CAP 10240            // fixed per-bucket edge capacity (mean 8192)
#define SS_CAP 11264             // ssrc per-bucket stride (padded lists, mult of 4)

typedef float f32x2 __attribute__((ext_vector_type(2)));

// fp8 e4m3 (OCP) helpers — gfx950 HW converters
__device__ inline f32x2 fp8_lo(unsigned int u) {
    return __builtin_amdgcn_cvt_pk_f32_fp8(u, false);   // bytes 0,1 -> 2 f32
}
__device__ inline f32x2 fp8_hi(unsigned int u) {
    return __builtin_amdgcn_cvt_pk_f32_fp8(u, true);    // bytes 2,3 -> 2 f32
}
__device__ inline unsigned int pack_fp8x2(float a, float b) {
    return __builtin_amdgcn_cvt_pk_fp8_f32(a, b, 0, false) & 0xFFFFu;
}

// ---------------- init: prefold + bcur init + ht sentinel rows ----------------
__global__ void k_init(int* __restrict__ bcur, int nbkt,
                       const float* b1, const float* g1, const float* be1,
                       const float* m1, const float* v1,
                       const float* b2, const float* g2, const float* be2,
                       const float* m2, const float* v2,
                       const float* b3, const float* g3, const float* be3,
                       const float* m3, const float* v3,
                       const float* b4, float* __restrict__ scsh,
                       unsigned int* __restrict__ hta_z, unsigned int* __restrict__ htb_z) {
    int t = threadIdx.x;  // 256
    if (blockIdx.x == 0) {
        int layer = t >> 6, ch = t & 63;
        float sc, sh;
        if (layer == 3) { sc = 1.f; sh = b4[ch]; }
        else {
            const float* bb = layer == 0 ? b1 : layer == 1 ? b2 : b3;
            const float* gg = layer == 0 ? g1 : layer == 1 ? g2 : g3;
            const float* ee = layer == 0 ? be1 : layer == 1 ? be2 : be3;
            const float* mm = layer == 0 ? m1 : layer == 1 ? m2 : m3;
            const float* vv = layer == 0 ? v1 : layer == 1 ? v2 : v3;
            sc = gg[ch] * rsqrtf(vv[ch] + BN_EPS);
            sh = (bb[ch] - mm[ch]) * sc + ee[ch];
        }
        scsh[layer * 128 + ch] = sc;
        scsh[layer * 128 + 64 + ch] = sh;
        if (t < 16) hta_z[t] = 0u;               // zero sentinel rows (16 dwords each)
        else if (t < 32) htb_z[t - 16] = 0u;
    } else {
        int i = (blockIdx.x - 1) * 256 + t;
        if (i < nbkt) bcur[i] = i * BKT_CAP;
    }
}

// scatter packed (src | dlo<<24) into fixed-capacity buckets; int4 edge loads.
__global__ void k_mscat(const int* __restrict__ src, const int* __restrict__ dst,
                        int* __restrict__ bcur, unsigned int* __restrict__ ebuf,
                        int E, int nbkt) {
    __shared__ int hist[512];
    __shared__ int basel[512];
    int t = threadIdx.x;  // 512
    for (int i = t; i < nbkt; i += MS_THREADS) hist[i] = 0;
    __syncthreads();
    int e0 = blockIdx.x * EPB;
    const int4* src4 = (const int4*)src;
    const int4* dst4 = (const int4*)dst;
    int es[EPT], ed[EPT];
#pragma unroll
    for (int k = 0; k < EPT / 4; k++) {
        int i4 = (e0 >> 2) + t + k * MS_THREADS;
        int ebase = i4 << 2;
        if (ebase + 3 < E) {
            int4 sv = src4[i4];
            int4 dv = dst4[i4];
            es[4 * k + 0] = sv.x; ed[4 * k + 0] = dv.x;
            es[4 * k + 1] = sv.y; ed[4 * k + 1] = dv.y;
            es[4 * k + 2] = sv.z; ed[4 * k + 2] = dv.z;
            es[4 * k + 3] = sv.w; ed[4 * k + 3] = dv.w;
        } else {
#pragma unroll
            for (int j = 0; j < 4; j++) {
                int e = ebase + j;
                if (e < E) { es[4 * k + j] = src[e]; ed[4 * k + j] = dst[e]; }
                else { es[4 * k + j] = 0; ed[4 * k + j] = -1; }
            }
        }
    }
#pragma unroll
    for (int k = 0; k < EPT; k++)
        if (ed[k] >= 0) atomicAdd(&hist[ed[k] >> BKT_SHIFT], 1);
    __syncthreads();
    for (int i = t; i < nbkt; i += MS_THREADS) {
        int h = hist[i];
        basel[i] = h ? atomicAdd(&bcur[i], h) : 0;
    }
    __syncthreads();
#pragma unroll
    for (int k = 0; k < EPT; k++) {
        if (ed[k] >= 0) {
            int bkt = ed[k] >> BKT_SHIFT;
            int pos = atomicAdd(&basel[bkt], 1);
            if (pos < (bkt + 1) * BKT_CAP)
                ebuf[pos] = (unsigned int)es[k] | ((unsigned int)(ed[k] & 255) << 24);
        }
    }
}

// per-bucket finalize, single global pass: stage ebuf segment in LDS while
// histogramming; scan; write cnt/isq/rs; place ssrc from the LDS copy.
__global__ void k_bfin(const unsigned int* __restrict__ ebuf, const int* __restrict__ bcur,
                       int* __restrict__ cnt, float* __restrict__ isq, int* __restrict__ rs,
                       int* __restrict__ ssrc, int N) {
    __shared__ unsigned int ebl[BKT_CAP];   // 40KB stage
    __shared__ int h[256];
    __shared__ int sc[256];
    __shared__ int curl[256];
    int b = blockIdx.x;
    int t = threadIdx.x;  // 512 threads
    int base = b << 8;
    int s0 = b * BKT_CAP;
    int s0s = b * SS_CAP;
    int s1 = bcur[b];
    if (s1 > s0 + BKT_CAP) s1 = s0 + BKT_CAP;
    int len = s1 - s0;
    const uint4* eb4 = (const uint4*)ebuf;
    if (t < 256) h[t] = 0;
    __syncthreads();
    for (int i4 = (s0 >> 2) + t; (i4 << 2) < s1; i4 += 512) {
        int e = i4 << 2;
        uint4 w = eb4[i4];
        *((uint4*)&ebl[e - s0]) = w;
        if (e + 3 < s1) {
            atomicAdd(&h[w.x >> 24], 1);
            atomicAdd(&h[w.y >> 24], 1);
            atomicAdd(&h[w.z >> 24], 1);
            atomicAdd(&h[w.w >> 24], 1);
        } else {
            if (e + 0 < s1) atomicAdd(&h[w.x >> 24], 1);
            if (e + 1 < s1) atomicAdd(&h[w.y >> 24], 1);
            if (e + 2 < s1) atomicAdd(&h[w.z >> 24], 1);
        }
    }
    __syncthreads();
    int cp = 0;
    if (t < 256) { cp = (h[t] + 3) & ~3; sc[t] = cp; }
    __syncthreads();
    int x = cp;
    for (int off = 1; off < 256; off <<= 1) {
        int y = (t < 256 && t >= off) ? sc[t - off] : 0;
        __syncthreads();
        if (t < 256) { x += y; sc[t] = x; }
        __syncthreads();
    }
    if (t < 256) {
        int node = base + t;
        if (node < N) {
            int c = h[t];
            int start = s0s + sc[t] - cp;
            cnt[node] = cp;
            isq[node] = rsqrtf((float)c + 1.0f);
            rs[node] = start;
            curl[t] = start;
            for (int p = c; p < cp; p++) ssrc[start + p] = N;
        }
    }
    __syncthreads();
    for (int i = t; i < len; i += 512) {
        unsigned int w = ebl[i];
        int pos = atomicAdd(&curl[w >> 24], 1);
        ssrc[pos] = (int)(w & 0x00FFFFFFu);
    }
}

// ---------------- dense transform for layer 1 (x[N,3] @ W1, fp8 out) ----------------

__global__ void k_transform3(const float* __restrict__ x, const float* __restrict__ W,
                             const float* __restrict__ isq, unsigned short* __restrict__ out,
                             int N) {
    __shared__ float Ws[192];
    __shared__ float xs[4][4];
    int c = threadIdx.x, ty = threadIdx.y;
    int t = ty * 64 + c;
    if (t < 192) Ws[t] = W[t];
    int node = blockIdx.x * 4 + ty;
    if (c < 3 && node < N) xs[ty][c] = x[node * 3 + c];
    __syncthreads();
    if (node >= N) return;
    float acc = xs[ty][0] * Ws[c] + xs[ty][1] * Ws[64 + c] + xs[ty][2] * Ws[128 + c];
    acc *= isq[node];
    float partner = __shfl_xor(acc, 1);
    if (!(c & 1)) out[node * 32 + (c >> 1)] = (unsigned short)pack_fp8x2(acc, partner);
}

// ---------------- fused aggregate + BN/ReLU/residual [+ next-layer transform] ----------
// One node per 16-lane group (16 nodes / 256-thr block). If FUSET: after the
// epilogue, the block computes ht_next = fp8(isq * x @ Wn) from LDS.
// hs padded to stride 68 so the 4 node-groups of a wave hit disjoint banks.
// OUTW=false skips the trunk write (layer 3: x3 feeds only the fused conv4).
// MODE 0: relu; 1: relu+res; 2: plain.
template <int MODE, bool FUSET, bool OUTW>
__global__ void k_rowwave(const unsigned int* __restrict__ ht8, const int* __restrict__ rs,
                          const int* __restrict__ cnt, const int* __restrict__ ssrc,
                          const float* __restrict__ isq,
                          const float* __restrict__ sc, const float* __restrict__ sh,
                          const float* __restrict__ xres,
                          float* __restrict__ out,
                          const float* __restrict__ Wn, unsigned int* __restrict__ htn,
                          int N) {
    __shared__ float Ws[FUSET ? 4096 : 1];
    __shared__ float hs[FUSET ? 16 : 1][FUSET ? 68 : 1];
    int tid = threadIdx.x;
    int cl = tid & 15;               // channel quad (4 fp8 = 1 dword)
    int nl = tid >> 4;
    int node = (blockIdx.x << 4) + nl;
    bool valid = node < N;
    if (FUSET) {
        const float4* W4p = (const float4*)Wn;
        float4* Ws4 = (float4*)Ws;
        for (int i = tid; i < 1024; i += 256) Ws4[i] = W4p[i];
    }
    float4 A = make_float4(0.f, 0.f, 0.f, 0.f);
    float q = 0.f;
    if (valid) {
        f32x2 a0l = {0.f, 0.f}, a0h = {0.f, 0.f};
        f32x2 a1l = {0.f, 0.f}, a1h = {0.f, 0.f};
        f32x2 a2l = {0.f, 0.f}, a2h = {0.f, 0.f};
        f32x2 a3l = {0.f, 0.f}, a3h = {0.f, 0.f};
        {   // self-loop
            unsigned int u = ht8[node * 16 + cl];
            a0l += fp8_lo(u); a0h += fp8_hi(u);
        }
        int st = rs[node];
        int nch = cnt[node] >> 2;        // int4 chunks (padded)
        const int4* ip = (const int4*)(ssrc + st);
        for (int ch = 0; ch < nch; ch++) {
            int4 s = ip[ch];             // broadcast within group
            unsigned int u0 = ht8[s.x * 16 + cl];
            unsigned int u1 = ht8[s.y * 16 + cl];
            unsigned int u2 = ht8[s.z * 16 + cl];
            unsigned int u3 = ht8[s.w * 16 + cl];
            a0l += fp8_lo(u0); a0h += fp8_hi(u0);
            a1l += fp8_lo(u1); a1h += fp8_hi(u1);
            a2l += fp8_lo(u2); a2h += fp8_hi(u2);
            a3l += fp8_lo(u3); a3h += fp8_hi(u3);
        }
        f32x2 al = (a0l + a1l) + (a2l + a3l);
        f32x2 ah = (a0h + a1h) + (a2h + a3h);
        A = make_float4(al.x, al.y, ah.x, ah.y);
        q = isq[node];
        float4 scv = ((const float4*)sc)[cl];
        float4 shv = ((const float4*)sh)[cl];
        A.x = fmaf(A.x * q, scv.x, shv.x);
        A.y = fmaf(A.y * q, scv.y, shv.y);
        A.z = fmaf(A.z * q, scv.z, shv.z);
        A.w = fmaf(A.w * q, scv.w, shv.w);
        if (MODE < 2) {
            A.x = fmaxf(A.x, 0.f); A.y = fmaxf(A.y, 0.f);
            A.z = fmaxf(A.z, 0.f); A.w = fmaxf(A.w, 0.f);
            if (MODE == 1) {
                float4 r = ((const float4*)(xres + node * 64))[cl];
                A.x += r.x; A.y += r.y; A.z += r.z; A.w += r.w;
            }
        }
        if (OUTW) ((float4*)(out + node * 64))[cl] = A;
    }
    if (FUSET) {
        hs[nl][4 * cl + 0] = A.x;
        hs[nl][4 * cl + 1] = A.y;
        hs[nl][4 * cl + 2] = A.z;
        hs[nl][4 * cl + 3] = A.w;
        __syncthreads();
        if (valid) {
            const float4* hrow = (const float4*)&hs[nl][0];   // stride 68: 16B-aligned
            float4 acc = make_float4(0.f, 0.f, 0.f, 0.f);
#pragma unroll
            for (int k4 = 0; k4 < 16; k4++) {
                float4 hv = hrow[k4];
                float4 w0 = ((const float4*)&Ws[(4 * k4 + 0) * 64])[cl];
                float4 w1 = ((const float4*)&Ws[(4 * k4 + 1) * 64])[cl];
                float4 w2 = ((const float4*)&Ws[(4 * k4 + 2) * 64])[cl];
                float4 w3 = ((const float4*)&Ws[(4 * k4 + 3) * 64])[cl];
                acc.x = fmaf(hv.x, w0.x, acc.x); acc.y = fmaf(hv.x, w0.y, acc.y);
                acc.z = fmaf(hv.x, w0.z, acc.z); acc.w = fmaf(hv.x, w0.w, acc.w);
                acc.x = fmaf(hv.y, w1.x, acc.x); acc.y = fmaf(hv.y, w1.y, acc.y);
                acc.z = fmaf(hv.y, w1.z, acc.z); acc.w = fmaf(hv.y, w1.w, acc.w);
                acc.x = fmaf(hv.z, w2.x, acc.x); acc.y = fmaf(hv.z, w2.y, acc.y);
                acc.z = fmaf(hv.z, w2.z, acc.z); acc.w = fmaf(hv.z, w2.w, acc.w);
                acc.x = fmaf(hv.w, w3.x, acc.x); acc.y = fmaf(hv.w, w3.y, acc.y);
                acc.z = fmaf(hv.w, w3.z, acc.z); acc.w = fmaf(hv.w, w3.w, acc.w);
            }
            acc.x *= q; acc.y *= q; acc.z *= q; acc.w *= q;
            unsigned int lo = pack_fp8x2(acc.x, acc.y);
            unsigned int hi = pack_fp8x2(acc.z, acc.w);
            htn[node * 16 + cl] = lo | (hi << 16);
        }
    }
}

// ---------------- fused pool + MLP head + log_softmax (one block per graph) ----------------

__device__ inline int lbound(const int* __restrict__ a, int n, int key) {
    int lo = 0, hi = n;
    while (lo < hi) {
        int mid = (lo + hi) >> 1;
        if (a[mid] < key) lo = mid + 1; else hi = mid;
    }
    return lo;
}

__global__ void k_poolhead(const float* __restrict__ x4, const int* __restrict__ batch,
                           const float* __restrict__ lw1, const float* __restrict__ lb1,
                           const float* __restrict__ lw2, const float* __restrict__ lb2,
                           float* __restrict__ out, int N) {
    __shared__ float w1s[2048];
    __shared__ float ps[64];
    int g = blockIdx.x;
    int c = threadIdx.x;  // 64 threads
    for (int i = c; i < 2048; i += 64) w1s[i] = lw1[i];
    int lo = lbound(batch, N, g);
    int hi = lbound(batch, N, g + 1);
    float s0 = 0.f, s1 = 0.f, s2 = 0.f, s3 = 0.f;
    int i = lo;
    for (; i + 3 < hi; i += 4) {
        s0 += x4[i * 64 + c];
        s1 += x4[(i + 1) * 64 + c];
        s2 += x4[(i + 2) * 64 + c];
        s3 += x4[(i + 3) * 64 + c];
    }
    for (; i < hi; i++) s0 += x4[i * 64 + c];
    ps[c] = ((s0 + s1) + (s2 + s3)) / fmaxf((float)(hi - lo), 1.0f);
    __syncthreads();
    float l0 = 0.f, l1 = 0.f;
    if (c < 32) {
        float hj = lb1[c];
#pragma unroll
        for (int k = 0; k < 64; k++) hj = fmaf(ps[k], w1s[k * 32 + c], hj);
        hj = fmaxf(hj, 0.f);
        l0 = hj * lw2[c * 2 + 0];
        l1 = hj * lw2[c * 2 + 1];
    }
#pragma unroll
    for (int off = 16; off >= 1; off >>= 1) {
        l0 += __shfl_down(l0, off);
        l1 += __shfl_down(l1, off);
    }
    if (c == 0) {
        l0 += lb2[0]; l1 += lb2[1];
        float mx = fmaxf(l0, l1);
        float lse = mx + logf(expf(l0 - mx) + expf(l1 - mx));
        out[g * 2 + 0] = l0 - lse;
        out[g * 2 + 1] = l1 - lse;
    }
}

// ---------------- launch ----------------

extern "C" void kernel_launch(void* const* d_in, const int* in_sizes, int n_in,
                              void* d_out, int out_size, void* d_ws, size_t ws_size,
                              hipStream_t stream) {
    const float* x   = (const float*)d_in[0];
    const float* W1  = (const float*)d_in[1];
    const float* b1  = (const float*)d_in[2];
    const float* W2  = (const float*)d_in[3];
    const float* b2  = (const float*)d_in[4];
    const float* W3  = (const float*)d_in[5];
    const float* b3  = (const float*)d_in[6];
    const float* W4  = (const float*)d_in[7];
    const float* b4  = (const float*)d_in[8];
    const float* g1  = (const float*)d_in[9];
    const float* be1 = (const float*)d_in[10];
    const float* m1  = (const float*)d_in[11];
    const float* v1  = (const float*)d_in[12];
    const float* g2  = (const float*)d_in[13];
    const float* be2 = (const float*)d_in[14];
    const float* m2  = (const float*)d_in[15];
    const float* v2  = (const float*)d_in[16];
    const float* g3  = (const float*)d_in[17];
    const float* be3 = (const float*)d_in[18];
    const float* m3  = (const float*)d_in[19];
    const float* v3  = (const float*)d_in[20];
    const float* lw1 = (const float*)d_in[21];
    const float* lb1 = (const float*)d_in[22];
    const float* lw2 = (const float*)d_in[23];
    const float* lb2 = (const float*)d_in[24];
    const int* src   = (const int*)d_in[25];
    const int* dst   = (const int*)d_in[26];
    const int* batch = (const int*)d_in[27];

    const int N = in_sizes[0] / 3;
    const int E = in_sizes[25];
    const int G = out_size / 2;

    char* w = (char*)d_ws;
    size_t off = 0;
    auto carve = [&](size_t bytes) -> void* {
        void* p = w + off;
        off = (off + bytes + 255) & ~(size_t)255;
        return p;
    };
    const int nbkt = (N + 255) >> BKT_SHIFT;
    int*   cnt     = (int*)  carve((size_t)N * 4);
    float* isq     = (float*)carve((size_t)N * 4);
    int*   rs      = (int*)  carve((size_t)N * 4);
    int*   bcur    = (int*)  carve(1024 * 4);
    float* scsh    = (float*)carve(8 * 64 * 4);
    int*   ssrc    = (int*)  carve((size_t)nbkt * SS_CAP * 4);
    unsigned int* ebuf = (unsigned int*)carve((size_t)nbkt * BKT_CAP * 4);
    unsigned int* hta = (unsigned int*)carve((size_t)(N + 1) * 64);  // fp8 rows + zero row
    unsigned int* htb = (unsigned int*)carve((size_t)(N + 1) * 64);
    float* xa      = (float*)carve((size_t)N * 64 * 4);
    float* xb      = (float*)carve((size_t)N * 64 * 4);
    (void)ws_size; (void)n_in;

    const int nbNode4 = (N + 3) / 4;
    const int nbNode16 = (N + 15) / 16;
    const int nbMs = (E + EPB - 1) / EPB;
    float* outp = (float*)d_out;

    // init (prefold + bcur + ht sentinels) + bucket build
    k_init<<<1 + (nbkt + 255) / 256, 256, 0, stream>>>(bcur, nbkt,
                                  b1, g1, be1, m1, v1, b2, g2, be2, m2, v2,
                                  b3, g3, be3, m3, v3, b4, scsh,
                                  hta + (size_t)N * 16, htb + (size_t)N * 16);
    k_mscat<<<nbMs, MS_THREADS, 0, stream>>>(src, dst, bcur, ebuf, E, nbkt);
    k_bfin<<<nbkt, 512, 0, stream>>>(ebuf, bcur, cnt, isq, rs, ssrc, N);

    dim3 tb(64, 4);

    // layer 1: x -> hta(fp8); rowwave1 -> xa + htb (= fp8(isq * xa @ W2))
    k_transform3<<<nbNode4, tb, 0, stream>>>(x, W1, isq, (unsigned short*)hta, N);
    k_rowwave<0, true, true><<<nbNode16, 256, 0, stream>>>(hta, rs, cnt, ssrc, isq,
                                               scsh + 0, scsh + 64, nullptr, xa, W2, htb, N);
    // layer 2: rowwave2 -> xb (+res xa) + hta (= fp8(isq * xb @ W3))
    k_rowwave<1, true, true><<<nbNode16, 256, 0, stream>>>(htb, rs, cnt, ssrc, isq,
                                               scsh + 128, scsh + 192, xa, xb, W3, hta, N);
    // layer 3: rowwave3 -> (+res xb, trunk write skipped) + htb (= fp8(isq * x3 @ W4))
    k_rowwave<1, true, false><<<nbNode16, 256, 0, stream>>>(hta, rs, cnt, ssrc, isq,
                                               scsh + 256, scsh + 320, xb, xa, W4, htb, N);
    // layer 4: rowwave4 -> xb (plain)
    k_rowwave<2, false, true><<<nbNode16, 256, 0, stream>>>(htb, rs, cnt, ssrc, isq,
                                               scsh + 384, scsh + 448, nullptr, xb,
                                               nullptr, nullptr, N);

    // fused pool + head
    k_poolhead<<<G, 64, 0, stream>>>(xb, batch, lw1, lb1, lw2, lb2, outp, N);
}

// Round 22
// 309.437 us; speedup vs baseline: 1.4885x; 1.0247x over previous
//
#include <hip/hip_runtime.h>
#include <math.h>

#define BN_EPS 1e-5f
#define EPT 4
#define MS_THREADS 512
#define EPB (MS_THREADS * EPT)   // 2048 edges per mscat block
#define BKT_SHIFT 8              // 256 nodes per bucket
#define BKT_CAP 10240            // fixed per-bucket edge capacity (mean 8192)
#define SS_CAP 11264             // ssrc per-bucket stride (padded lists, mult of 4)

typedef float f32x2 __attribute__((ext_vector_type(2)));

// fp8 e4m3 (OCP) helpers — gfx950 HW converters
__device__ inline f32x2 fp8_lo(unsigned int u) {
    return __builtin_amdgcn_cvt_pk_f32_fp8(u, false);   // bytes 0,1 -> 2 f32
}
__device__ inline f32x2 fp8_hi(unsigned int u) {
    return __builtin_amdgcn_cvt_pk_f32_fp8(u, true);    // bytes 2,3 -> 2 f32
}
__device__ inline unsigned int pack_fp8x2(float a, float b) {
    return __builtin_amdgcn_cvt_pk_fp8_f32(a, b, 0, false) & 0xFFFFu;
}

// ---------------- init: prefold + bcur init + ht sentinel rows ----------------
__global__ void k_init(int* __restrict__ bcur, int nbkt,
                       const float* b1, const float* g1, const float* be1,
                       const float* m1, const float* v1,
                       const float* b2, const float* g2, const float* be2,
                       const float* m2, const float* v2,
                       const float* b3, const float* g3, const float* be3,
                       const float* m3, const float* v3,
                       const float* b4, float* __restrict__ scsh,
                       unsigned int* __restrict__ hta_z, unsigned int* __restrict__ htb_z) {
    int t = threadIdx.x;  // 256
    if (blockIdx.x == 0) {
        int layer = t >> 6, ch = t & 63;
        float sc, sh;
        if (layer == 3) { sc = 1.f; sh = b4[ch]; }
        else {
            const float* bb = layer == 0 ? b1 : layer == 1 ? b2 : b3;
            const float* gg = layer == 0 ? g1 : layer == 1 ? g2 : g3;
            const float* ee = layer == 0 ? be1 : layer == 1 ? be2 : be3;
            const float* mm = layer == 0 ? m1 : layer == 1 ? m2 : m3;
            const float* vv = layer == 0 ? v1 : layer == 1 ? v2 : v3;
            sc = gg[ch] * rsqrtf(vv[ch] + BN_EPS);
            sh = (bb[ch] - mm[ch]) * sc + ee[ch];
        }
        scsh[layer * 128 + ch] = sc;
        scsh[layer * 128 + 64 + ch] = sh;
        if (t < 16) hta_z[t] = 0u;               // zero sentinel rows (16 dwords each)
        else if (t < 32) htb_z[t - 16] = 0u;
    } else {
        int i = (blockIdx.x - 1) * 256 + t;
        if (i < nbkt) bcur[i] = i * BKT_CAP;
    }
}

// scatter packed (src | dlo<<24) into fixed-capacity buckets; int4 edge loads.
__global__ void k_mscat(const int* __restrict__ src, const int* __restrict__ dst,
                        int* __restrict__ bcur, unsigned int* __restrict__ ebuf,
                        int E, int nbkt) {
    __shared__ int hist[512];
    __shared__ int basel[512];
    int t = threadIdx.x;  // 512
    for (int i = t; i < nbkt; i += MS_THREADS) hist[i] = 0;
    __syncthreads();
    int e0 = blockIdx.x * EPB;
    const int4* src4 = (const int4*)src;
    const int4* dst4 = (const int4*)dst;
    int es[EPT], ed[EPT];
#pragma unroll
    for (int k = 0; k < EPT / 4; k++) {
        int i4 = (e0 >> 2) + t + k * MS_THREADS;
        int ebase = i4 << 2;
        if (ebase + 3 < E) {
            int4 sv = src4[i4];
            int4 dv = dst4[i4];
            es[4 * k + 0] = sv.x; ed[4 * k + 0] = dv.x;
            es[4 * k + 1] = sv.y; ed[4 * k + 1] = dv.y;
            es[4 * k + 2] = sv.z; ed[4 * k + 2] = dv.z;
            es[4 * k + 3] = sv.w; ed[4 * k + 3] = dv.w;
        } else {
#pragma unroll
            for (int j = 0; j < 4; j++) {
                int e = ebase + j;
                if (e < E) { es[4 * k + j] = src[e]; ed[4 * k + j] = dst[e]; }
                else { es[4 * k + j] = 0; ed[4 * k + j] = -1; }
            }
        }
    }
#pragma unroll
    for (int k = 0; k < EPT; k++)
        if (ed[k] >= 0) atomicAdd(&hist[ed[k] >> BKT_SHIFT], 1);
    __syncthreads();
    for (int i = t; i < nbkt; i += MS_THREADS) {
        int h = hist[i];
        basel[i] = h ? atomicAdd(&bcur[i], h) : 0;
    }
    __syncthreads();
#pragma unroll
    for (int k = 0; k < EPT; k++) {
        if (ed[k] >= 0) {
            int bkt = ed[k] >> BKT_SHIFT;
            int pos = atomicAdd(&basel[bkt], 1);
            if (pos < (bkt + 1) * BKT_CAP)
                ebuf[pos] = (unsigned int)es[k] | ((unsigned int)(ed[k] & 255) << 24);
        }
    }
}

// per-bucket finalize, single global pass: stage ebuf segment in LDS while
// histogramming; scan; write cnt/isq/rs; place ssrc from the LDS copy.
__global__ void k_bfin(const unsigned int* __restrict__ ebuf, const int* __restrict__ bcur,
                       int* __restrict__ cnt, float* __restrict__ isq, int* __restrict__ rs,
                       int* __restrict__ ssrc, int N) {
    __shared__ unsigned int ebl[BKT_CAP];   // 40KB stage
    __shared__ int h[256];
    __shared__ int sc[256];
    __shared__ int curl[256];
    int b = blockIdx.x;
    int t = threadIdx.x;  // 512 threads
    int base = b << 8;
    int s0 = b * BKT_CAP;
    int s0s = b * SS_CAP;
    int s1 = bcur[b];
    if (s1 > s0 + BKT_CAP) s1 = s0 + BKT_CAP;
    int len = s1 - s0;
    const uint4* eb4 = (const uint4*)ebuf;
    if (t < 256) h[t] = 0;
    __syncthreads();
    for (int i4 = (s0 >> 2) + t; (i4 << 2) < s1; i4 += 512) {
        int e = i4 << 2;
        uint4 w = eb4[i4];
        *((uint4*)&ebl[e - s0]) = w;
        if (e + 3 < s1) {
            atomicAdd(&h[w.x >> 24], 1);
            atomicAdd(&h[w.y >> 24], 1);
            atomicAdd(&h[w.z >> 24], 1);
            atomicAdd(&h[w.w >> 24], 1);
        } else {
            if (e + 0 < s1) atomicAdd(&h[w.x >> 24], 1);
            if (e + 1 < s1) atomicAdd(&h[w.y >> 24], 1);
            if (e + 2 < s1) atomicAdd(&h[w.z >> 24], 1);
        }
    }
    __syncthreads();
    int cp = 0;
    if (t < 256) { cp = (h[t] + 3) & ~3; sc[t] = cp; }
    __syncthreads();
    int x = cp;
    for (int off = 1; off < 256; off <<= 1) {
        int y = (t < 256 && t >= off) ? sc[t - off] : 0;
        __syncthreads();
        if (t < 256) { x += y; sc[t] = x; }
        __syncthreads();
    }
    if (t < 256) {
        int node = base + t;
        if (node < N) {
            int c = h[t];
            int start = s0s + sc[t] - cp;
            cnt[node] = cp;
            isq[node] = rsqrtf((float)c + 1.0f);
            rs[node] = start;
            curl[t] = start;
            for (int p = c; p < cp; p++) ssrc[start + p] = N;
        }
    }
    __syncthreads();
    for (int i = t; i < len; i += 512) {
        unsigned int w = ebl[i];
        int pos = atomicAdd(&curl[w >> 24], 1);
        ssrc[pos] = (int)(w & 0x00FFFFFFu);
    }
}

// ---------------- dense transform for layer 1 (x[N,3] @ W1, fp8 out) ----------------

__global__ void k_transform3(const float* __restrict__ x, const float* __restrict__ W,
                             const float* __restrict__ isq, unsigned short* __restrict__ out,
                             int N) {
    __shared__ float Ws[192];
    __shared__ float xs[4][4];
    int c = threadIdx.x, ty = threadIdx.y;
    int t = ty * 64 + c;
    if (t < 192) Ws[t] = W[t];
    int node = blockIdx.x * 4 + ty;
    if (c < 3 && node < N) xs[ty][c] = x[node * 3 + c];
    __syncthreads();
    if (node >= N) return;
    float acc = xs[ty][0] * Ws[c] + xs[ty][1] * Ws[64 + c] + xs[ty][2] * Ws[128 + c];
    acc *= isq[node];
    float partner = __shfl_xor(acc, 1);
    if (!(c & 1)) out[node * 32 + (c >> 1)] = (unsigned short)pack_fp8x2(acc, partner);
}

// ---------------- fused aggregate + BN/ReLU/residual [+ transform | pool] ----------
// One node per 16-lane group (16 nodes / 256-thr block).
// FUSET: compute ht_next = fp8(isq * x @ Wn) from LDS (hs stride 68, bank-clean).
// FUSEP: segmented-reduce A over the block's (sorted-batch) nodes, atomicAdd into
//        pooled (L2-resident); replaces the trunk write + pool pass.
// OUTW=false skips the trunk write. MODE 0: relu; 1: relu+res; 2: plain.
template <int MODE, bool FUSET, bool OUTW, bool FUSEP>
__global__ void k_rowwave(const unsigned int* __restrict__ ht8, const int* __restrict__ rs,
                          const int* __restrict__ cnt, const int* __restrict__ ssrc,
                          const float* __restrict__ isq,
                          const float* __restrict__ sc, const float* __restrict__ sh,
                          const float* __restrict__ xres,
                          float* __restrict__ out,
                          const float* __restrict__ Wn, unsigned int* __restrict__ htn,
                          const int* __restrict__ batch, float* __restrict__ pooled,
                          int N) {
    __shared__ float Ws[FUSET ? 4096 : 1];
    __shared__ float hs[(FUSET || FUSEP) ? 16 : 1][(FUSET || FUSEP) ? 68 : 1];
    __shared__ int sgl[FUSEP ? 16 : 1];
    int tid = threadIdx.x;
    int cl = tid & 15;               // channel quad (4 fp8 = 1 dword)
    int nl = tid >> 4;
    int node = (blockIdx.x << 4) + nl;
    bool valid = node < N;
    if (FUSET) {
        const float4* W4p = (const float4*)Wn;
        float4* Ws4 = (float4*)Ws;
        for (int i = tid; i < 1024; i += 256) Ws4[i] = W4p[i];
    }
    float4 A = make_float4(0.f, 0.f, 0.f, 0.f);
    float q = 0.f;
    if (valid) {
        f32x2 a0l = {0.f, 0.f}, a0h = {0.f, 0.f};
        f32x2 a1l = {0.f, 0.f}, a1h = {0.f, 0.f};
        f32x2 a2l = {0.f, 0.f}, a2h = {0.f, 0.f};
        f32x2 a3l = {0.f, 0.f}, a3h = {0.f, 0.f};
        {   // self-loop
            unsigned int u = ht8[node * 16 + cl];
            a0l += fp8_lo(u); a0h += fp8_hi(u);
        }
        int st = rs[node];
        int nch = cnt[node] >> 2;        // int4 chunks (padded)
        const int4* ip = (const int4*)(ssrc + st);
        for (int ch = 0; ch < nch; ch++) {
            int4 s = ip[ch];             // broadcast within group
            unsigned int u0 = ht8[s.x * 16 + cl];
            unsigned int u1 = ht8[s.y * 16 + cl];
            unsigned int u2 = ht8[s.z * 16 + cl];
            unsigned int u3 = ht8[s.w * 16 + cl];
            a0l += fp8_lo(u0); a0h += fp8_hi(u0);
            a1l += fp8_lo(u1); a1h += fp8_hi(u1);
            a2l += fp8_lo(u2); a2h += fp8_hi(u2);
            a3l += fp8_lo(u3); a3h += fp8_hi(u3);
        }
        f32x2 al = (a0l + a1l) + (a2l + a3l);
        f32x2 ah = (a0h + a1h) + (a2h + a3h);
        A = make_float4(al.x, al.y, ah.x, ah.y);
        q = isq[node];
        float4 scv = ((const float4*)sc)[cl];
        float4 shv = ((const float4*)sh)[cl];
        A.x = fmaf(A.x * q, scv.x, shv.x);
        A.y = fmaf(A.y * q, scv.y, shv.y);
        A.z = fmaf(A.z * q, scv.z, shv.z);
        A.w = fmaf(A.w * q, scv.w, shv.w);
        if (MODE < 2) {
            A.x = fmaxf(A.x, 0.f); A.y = fmaxf(A.y, 0.f);
            A.z = fmaxf(A.z, 0.f); A.w = fmaxf(A.w, 0.f);
            if (MODE == 1) {
                float4 r = ((const float4*)(xres + node * 64))[cl];
                A.x += r.x; A.y += r.y; A.z += r.z; A.w += r.w;
            }
        }
        if (OUTW) ((float4*)(out + node * 64))[cl] = A;
    }
    if (FUSET || FUSEP) {
        hs[nl][4 * cl + 0] = A.x;
        hs[nl][4 * cl + 1] = A.y;
        hs[nl][4 * cl + 2] = A.z;
        hs[nl][4 * cl + 3] = A.w;
        if (FUSEP && cl == 0) sgl[nl] = valid ? batch[node] : -1;
        __syncthreads();
    }
    if (FUSET) {
        if (valid) {
            const float4* hrow = (const float4*)&hs[nl][0];   // stride 68: 16B-aligned
            float4 acc = make_float4(0.f, 0.f, 0.f, 0.f);
#pragma unroll
            for (int k4 = 0; k4 < 16; k4++) {
                float4 hv = hrow[k4];
                float4 w0 = ((const float4*)&Ws[(4 * k4 + 0) * 64])[cl];
                float4 w1 = ((const float4*)&Ws[(4 * k4 + 1) * 64])[cl];
                float4 w2 = ((const float4*)&Ws[(4 * k4 + 2) * 64])[cl];
                float4 w3 = ((const float4*)&Ws[(4 * k4 + 3) * 64])[cl];
                acc.x = fmaf(hv.x, w0.x, acc.x); acc.y = fmaf(hv.x, w0.y, acc.y);
                acc.z = fmaf(hv.x, w0.z, acc.z); acc.w = fmaf(hv.x, w0.w, acc.w);
                acc.x = fmaf(hv.y, w1.x, acc.x); acc.y = fmaf(hv.y, w1.y, acc.y);
                acc.z = fmaf(hv.y, w1.z, acc.z); acc.w = fmaf(hv.y, w1.w, acc.w);
                acc.x = fmaf(hv.z, w2.x, acc.x); acc.y = fmaf(hv.z, w2.y, acc.y);
                acc.z = fmaf(hv.z, w2.z, acc.z); acc.w = fmaf(hv.z, w2.w, acc.w);
                acc.x = fmaf(hv.w, w3.x, acc.x); acc.y = fmaf(hv.w, w3.y, acc.y);
                acc.z = fmaf(hv.w, w3.z, acc.z); acc.w = fmaf(hv.w, w3.w, acc.w);
            }
            acc.x *= q; acc.y *= q; acc.z *= q; acc.w *= q;
            unsigned int lo = pack_fp8x2(acc.x, acc.y);
            unsigned int hi = pack_fp8x2(acc.z, acc.w);
            htn[node * 16 + cl] = lo | (hi << 16);
        }
    }
    if (FUSEP) {
        if (tid < 64) {
            int c = tid;
            float sum = 0.f;
            int curg = sgl[0];
            for (int r = 0; r < 16; r++) {
                int g = sgl[r];
                if (g != curg) {
                    if (curg >= 0) atomicAdd(&pooled[curg * 64 + c], sum);
                    sum = 0.f;
                    curg = g;
                }
                if (g >= 0) sum += hs[r][c];
            }
            if (curg >= 0) atomicAdd(&pooled[curg * 64 + c], sum);
        }
    }
}

// ---------------- head: mean-divide + MLP + log_softmax (one block per graph) ----------

__device__ inline int lbound(const int* __restrict__ a, int n, int key) {
    int lo = 0, hi = n;
    while (lo < hi) {
        int mid = (lo + hi) >> 1;
        if (a[mid] < key) lo = mid + 1; else hi = mid;
    }
    return lo;
}

__global__ void k_head(const float* __restrict__ pooled, const int* __restrict__ batch,
                       const float* __restrict__ lw1, const float* __restrict__ lb1,
                       const float* __restrict__ lw2, const float* __restrict__ lb2,
                       float* __restrict__ out, int N) {
    __shared__ float w1s[2048];
    __shared__ float ps[64];
    int g = blockIdx.x;
    int c = threadIdx.x;  // 64 threads
    for (int i = c; i < 2048; i += 64) w1s[i] = lw1[i];
    int lo = lbound(batch, N, g);
    int hi = lbound(batch, N, g + 1);
    ps[c] = pooled[g * 64 + c] / fmaxf((float)(hi - lo), 1.0f);
    __syncthreads();
    float l0 = 0.f, l1 = 0.f;
    if (c < 32) {
        float hj = lb1[c];
#pragma unroll
        for (int k = 0; k < 64; k++) hj = fmaf(ps[k], w1s[k * 32 + c], hj);
        hj = fmaxf(hj, 0.f);
        l0 = hj * lw2[c * 2 + 0];
        l1 = hj * lw2[c * 2 + 1];
    }
#pragma unroll
    for (int off = 16; off >= 1; off >>= 1) {
        l0 += __shfl_down(l0, off);
        l1 += __shfl_down(l1, off);
    }
    if (c == 0) {
        l0 += lb2[0]; l1 += lb2[1];
        float mx = fmaxf(l0, l1);
        float lse = mx + logf(expf(l0 - mx) + expf(l1 - mx));
        out[g * 2 + 0] = l0 - lse;
        out[g * 2 + 1] = l1 - lse;
    }
}

// ---------------- launch ----------------

extern "C" void kernel_launch(void* const* d_in, const int* in_sizes, int n_in,
                              void* d_out, int out_size, void* d_ws, size_t ws_size,
                              hipStream_t stream) {
    const float* x   = (const float*)d_in[0];
    const float* W1  = (const float*)d_in[1];
    const float* b1  = (const float*)d_in[2];
    const float* W2  = (const float*)d_in[3];
    const float* b2  = (const float*)d_in[4];
    const float* W3  = (const float*)d_in[5];
    const float* b3  = (const float*)d_in[6];
    const float* W4  = (const float*)d_in[7];
    const float* b4  = (const float*)d_in[8];
    const float* g1  = (const float*)d_in[9];
    const float* be1 = (const float*)d_in[10];
    const float* m1  = (const float*)d_in[11];
    const float* v1  = (const float*)d_in[12];
    const float* g2  = (const float*)d_in[13];
    const float* be2 = (const float*)d_in[14];
    const float* m2  = (const float*)d_in[15];
    const float* v2  = (const float*)d_in[16];
    const float* g3  = (const float*)d_in[17];
    const float* be3 = (const float*)d_in[18];
    const float* m3  = (const float*)d_in[19];
    const float* v3  = (const float*)d_in[20];
    const float* lw1 = (const float*)d_in[21];
    const float* lb1 = (const float*)d_in[22];
    const float* lw2 = (const float*)d_in[23];
    const float* lb2 = (const float*)d_in[24];
    const int* src   = (const int*)d_in[25];
    const int* dst   = (const int*)d_in[26];
    const int* batch = (const int*)d_in[27];

    const int N = in_sizes[0] / 3;
    const int E = in_sizes[25];
    const int G = out_size / 2;

    char* w = (char*)d_ws;
    size_t off = 0;
    auto carve = [&](size_t bytes) -> void* {
        void* p = w + off;
        off = (off + bytes + 255) & ~(size_t)255;
        return p;
    };
    const int nbkt = (N + 255) >> BKT_SHIFT;
    int*   cnt     = (int*)  carve((size_t)N * 4);
    float* isq     = (float*)carve((size_t)N * 4);
    int*   rs      = (int*)  carve((size_t)N * 4);
    int*   bcur    = (int*)  carve(1024 * 4);
    float* scsh    = (float*)carve(8 * 64 * 4);
    int*   ssrc    = (int*)  carve((size_t)nbkt * SS_CAP * 4);
    unsigned int* ebuf = (unsigned int*)carve((size_t)nbkt * BKT_CAP * 4);
    unsigned int* hta = (unsigned int*)carve((size_t)(N + 1) * 64);  // fp8 rows + zero row
    unsigned int* htb = (unsigned int*)carve((size_t)(N + 1) * 64);
    float* xa      = (float*)carve((size_t)N * 64 * 4);
    float* xb      = (float*)carve((size_t)N * 64 * 4);
    float* pooled  = (float*)carve((size_t)G * 64 * 4);
    (void)ws_size; (void)n_in;

    const int nbNode4 = (N + 3) / 4;
    const int nbNode16 = (N + 15) / 16;
    const int nbMs = (E + EPB - 1) / EPB;
    float* outp = (float*)d_out;

    // init (prefold + bcur + ht sentinels) + bucket build; zero pooled accumulator
    k_init<<<1 + (nbkt + 255) / 256, 256, 0, stream>>>(bcur, nbkt,
                                  b1, g1, be1, m1, v1, b2, g2, be2, m2, v2,
                                  b3, g3, be3, m3, v3, b4, scsh,
                                  hta + (size_t)N * 16, htb + (size_t)N * 16);
    hipMemsetAsync(pooled, 0, (size_t)G * 64 * 4, stream);
    k_mscat<<<nbMs, MS_THREADS, 0, stream>>>(src, dst, bcur, ebuf, E, nbkt);
    k_bfin<<<nbkt, 512, 0, stream>>>(ebuf, bcur, cnt, isq, rs, ssrc, N);

    dim3 tb(64, 4);

    // layer 1: x -> hta(fp8); rowwave1 -> xa + htb (= fp8(isq * xa @ W2))
    k_transform3<<<nbNode4, tb, 0, stream>>>(x, W1, isq, (unsigned short*)hta, N);
    k_rowwave<0, true, true, false><<<nbNode16, 256, 0, stream>>>(hta, rs, cnt, ssrc, isq,
                                               scsh + 0, scsh + 64, nullptr, xa, W2, htb,
                                               nullptr, nullptr, N);
    // layer 2: rowwave2 -> xb (+res xa) + hta (= fp8(isq * xb @ W3))
    k_rowwave<1, true, true, false><<<nbNode16, 256, 0, stream>>>(htb, rs, cnt, ssrc, isq,
                                               scsh + 128, scsh + 192, xa, xb, W3, hta,
                                               nullptr, nullptr, N);
    // layer 3: rowwave3 -> (+res xb, trunk write skipped) + htb (= fp8(isq * x3 @ W4))
    k_rowwave<1, true, false, false><<<nbNode16, 256, 0, stream>>>(hta, rs, cnt, ssrc, isq,
                                               scsh + 256, scsh + 320, xb, xa, W4, htb,
                                               nullptr, nullptr, N);
    // layer 4: rowwave4 -> pooled sums directly (no trunk write)
    k_rowwave<2, false, false, true><<<nbNode16, 256, 0, stream>>>(htb, rs, cnt, ssrc, isq,
                                               scsh + 384, scsh + 448, nullptr, nullptr,
                                               nullptr, nullptr, batch, pooled, N);

    // head: divide by counts + MLP + log_softmax
    k_head<<<G, 64, 0, stream>>>(pooled, batch, lw1, lb1, lw2, lb2, outp, N);
}

// Round 23
// 306.496 us; speedup vs baseline: 1.5028x; 1.0096x over previous
//
#include <hip/hip_runtime.h>
#include <math.h>

#define BN_EPS 1e-5f
#define EPT 4
#define MS_THREADS 512
#define EPB (MS_THREADS * EPT)   // 2048 edges per mscat block
#define BKT_SHIFT 8              // 256 nodes per bucket
#define BKT_CAP 10240            // fixed per-bucket edge capacity (mean 8192)
#define SS_CAP 11264             // ssrc per-bucket stride (padded lists, mult of 4)

typedef float f32x2 __attribute__((ext_vector_type(2)));

// fp8 e4m3 (OCP) helpers — gfx950 HW converters
__device__ inline f32x2 fp8_lo(unsigned int u) {
    return __builtin_amdgcn_cvt_pk_f32_fp8(u, false);   // bytes 0,1 -> 2 f32
}
__device__ inline f32x2 fp8_hi(unsigned int u) {
    return __builtin_amdgcn_cvt_pk_f32_fp8(u, true);    // bytes 2,3 -> 2 f32
}
__device__ inline unsigned int pack_fp8x2(float a, float b) {
    return __builtin_amdgcn_cvt_pk_fp8_f32(a, b, 0, false) & 0xFFFFu;
}

// bf16 helpers (RNE pack, shift unpack)
__device__ inline unsigned int f2bf(float f) {
    union { float f; unsigned int i; } x; x.f = f;
    unsigned int r = x.i + 0x7fffu + ((x.i >> 16) & 1u);
    return r >> 16;
}
__device__ inline float u2f(unsigned int u) {
    union { unsigned int i; float f; } x; x.i = u; return x.f;
}

// ---------------- init: prefold + bcur init + ht sentinel rows ----------------
__global__ void k_init(int* __restrict__ bcur, int nbkt,
                       const float* b1, const float* g1, const float* be1,
                       const float* m1, const float* v1,
                       const float* b2, const float* g2, const float* be2,
                       const float* m2, const float* v2,
                       const float* b3, const float* g3, const float* be3,
                       const float* m3, const float* v3,
                       const float* b4, float* __restrict__ scsh,
                       unsigned int* __restrict__ hta_z, unsigned int* __restrict__ htb_z) {
    int t = threadIdx.x;  // 256
    if (blockIdx.x == 0) {
        int layer = t >> 6, ch = t & 63;
        float sc, sh;
        if (layer == 3) { sc = 1.f; sh = b4[ch]; }
        else {
            const float* bb = layer == 0 ? b1 : layer == 1 ? b2 : b3;
            const float* gg = layer == 0 ? g1 : layer == 1 ? g2 : g3;
            const float* ee = layer == 0 ? be1 : layer == 1 ? be2 : be3;
            const float* mm = layer == 0 ? m1 : layer == 1 ? m2 : m3;
            const float* vv = layer == 0 ? v1 : layer == 1 ? v2 : v3;
            sc = gg[ch] * rsqrtf(vv[ch] + BN_EPS);
            sh = (bb[ch] - mm[ch]) * sc + ee[ch];
        }
        scsh[layer * 128 + ch] = sc;
        scsh[layer * 128 + 64 + ch] = sh;
        if (t < 16) hta_z[t] = 0u;               // zero sentinel rows (16 dwords each)
        else if (t < 32) htb_z[t - 16] = 0u;
    } else {
        int i = (blockIdx.x - 1) * 256 + t;
        if (i < nbkt) bcur[i] = i * BKT_CAP;
    }
}

// scatter packed (src | dlo<<24) into fixed-capacity buckets; int4 edge loads.
__global__ void k_mscat(const int* __restrict__ src, const int* __restrict__ dst,
                        int* __restrict__ bcur, unsigned int* __restrict__ ebuf,
                        int E, int nbkt) {
    __shared__ int hist[512];
    __shared__ int basel[512];
    int t = threadIdx.x;  // 512
    for (int i = t; i < nbkt; i += MS_THREADS) hist[i] = 0;
    __syncthreads();
    int e0 = blockIdx.x * EPB;
    const int4* src4 = (const int4*)src;
    const int4* dst4 = (const int4*)dst;
    int es[EPT], ed[EPT];
#pragma unroll
    for (int k = 0; k < EPT / 4; k++) {
        int i4 = (e0 >> 2) + t + k * MS_THREADS;
        int ebase = i4 << 2;
        if (ebase + 3 < E) {
            int4 sv = src4[i4];
            int4 dv = dst4[i4];
            es[4 * k + 0] = sv.x; ed[4 * k + 0] = dv.x;
            es[4 * k + 1] = sv.y; ed[4 * k + 1] = dv.y;
            es[4 * k + 2] = sv.z; ed[4 * k + 2] = dv.z;
            es[4 * k + 3] = sv.w; ed[4 * k + 3] = dv.w;
        } else {
#pragma unroll
            for (int j = 0; j < 4; j++) {
                int e = ebase + j;
                if (e < E) { es[4 * k + j] = src[e]; ed[4 * k + j] = dst[e]; }
                else { es[4 * k + j] = 0; ed[4 * k + j] = -1; }
            }
        }
    }
#pragma unroll
    for (int k = 0; k < EPT; k++)
        if (ed[k] >= 0) atomicAdd(&hist[ed[k] >> BKT_SHIFT], 1);
    __syncthreads();
    for (int i = t; i < nbkt; i += MS_THREADS) {
        int h = hist[i];
        basel[i] = h ? atomicAdd(&bcur[i], h) : 0;
    }
    __syncthreads();
#pragma unroll
    for (int k = 0; k < EPT; k++) {
        if (ed[k] >= 0) {
            int bkt = ed[k] >> BKT_SHIFT;
            int pos = atomicAdd(&basel[bkt], 1);
            if (pos < (bkt + 1) * BKT_CAP)
                ebuf[pos] = (unsigned int)es[k] | ((unsigned int)(ed[k] & 255) << 24);
        }
    }
}

// per-bucket finalize, single global pass, 1024 threads for latency hiding:
// stage ebuf segment in LDS while histogramming; scan; write cnt/isq/rs;
// place ssrc from the LDS copy.
__global__ void __launch_bounds__(1024) k_bfin(
        const unsigned int* __restrict__ ebuf, const int* __restrict__ bcur,
        int* __restrict__ cnt, float* __restrict__ isq, int* __restrict__ rs,
        int* __restrict__ ssrc, int N) {
    __shared__ unsigned int ebl[BKT_CAP];   // 40KB stage
    __shared__ int h[256];
    __shared__ int sc[256];
    __shared__ int curl[256];
    int b = blockIdx.x;
    int t = threadIdx.x;  // 1024 threads
    int base = b << 8;
    int s0 = b * BKT_CAP;
    int s0s = b * SS_CAP;
    int s1 = bcur[b];
    if (s1 > s0 + BKT_CAP) s1 = s0 + BKT_CAP;
    int len = s1 - s0;
    const uint4* eb4 = (const uint4*)ebuf;
    if (t < 256) h[t] = 0;
    __syncthreads();
    for (int i4 = (s0 >> 2) + t; (i4 << 2) < s1; i4 += 1024) {
        int e = i4 << 2;
        uint4 w = eb4[i4];
        *((uint4*)&ebl[e - s0]) = w;
        if (e + 3 < s1) {
            atomicAdd(&h[w.x >> 24], 1);
            atomicAdd(&h[w.y >> 24], 1);
            atomicAdd(&h[w.z >> 24], 1);
            atomicAdd(&h[w.w >> 24], 1);
        } else {
            if (e + 0 < s1) atomicAdd(&h[w.x >> 24], 1);
            if (e + 1 < s1) atomicAdd(&h[w.y >> 24], 1);
            if (e + 2 < s1) atomicAdd(&h[w.z >> 24], 1);
        }
    }
    __syncthreads();
    int cp = 0;
    if (t < 256) { cp = (h[t] + 3) & ~3; sc[t] = cp; }
    __syncthreads();
    int x = cp;
    for (int off = 1; off < 256; off <<= 1) {
        int y = (t < 256 && t >= off) ? sc[t - off] : 0;
        __syncthreads();
        if (t < 256) { x += y; sc[t] = x; }
        __syncthreads();
    }
    if (t < 256) {
        int node = base + t;
        if (node < N) {
            int c = h[t];
            int start = s0s + sc[t] - cp;
            cnt[node] = cp;
            isq[node] = rsqrtf((float)c + 1.0f);
            rs[node] = start;
            curl[t] = start;
            for (int p = c; p < cp; p++) ssrc[start + p] = N;
        }
    }
    __syncthreads();
    for (int i = t; i < len; i += 1024) {
        unsigned int w = ebl[i];
        int pos = atomicAdd(&curl[w >> 24], 1);
        ssrc[pos] = (int)(w & 0x00FFFFFFu);
    }
}

// ---------------- dense transform for layer 1 (x[N,3] @ W1, fp8 out) ----------------

__global__ void k_transform3(const float* __restrict__ x, const float* __restrict__ W,
                             const float* __restrict__ isq, unsigned short* __restrict__ out,
                             int N) {
    __shared__ float Ws[192];
    __shared__ float xs[4][4];
    int c = threadIdx.x, ty = threadIdx.y;
    int t = ty * 64 + c;
    if (t < 192) Ws[t] = W[t];
    int node = blockIdx.x * 4 + ty;
    if (c < 3 && node < N) xs[ty][c] = x[node * 3 + c];
    __syncthreads();
    if (node >= N) return;
    float acc = xs[ty][0] * Ws[c] + xs[ty][1] * Ws[64 + c] + xs[ty][2] * Ws[128 + c];
    acc *= isq[node];
    float partner = __shfl_xor(acc, 1);
    if (!(c & 1)) out[node * 32 + (c >> 1)] = (unsigned short)pack_fp8x2(acc, partner);
}

// ---------------- fused aggregate + BN/ReLU/residual [+ transform | pool] ----------
// One node per 16-lane group (16 nodes / 256-thr block). Trunk (out/xres) is bf16
// (residual-only traffic). FUSET: ht_next = fp8(isq * x @ Wn) from LDS (stride-68,
// bank-clean). FUSEP: segmented-reduce into pooled via atomics.
// OUTW=false skips the trunk write. MODE 0: relu; 1: relu+res; 2: plain.
template <int MODE, bool FUSET, bool OUTW, bool FUSEP>
__global__ void k_rowwave(const unsigned int* __restrict__ ht8, const int* __restrict__ rs,
                          const int* __restrict__ cnt, const int* __restrict__ ssrc,
                          const float* __restrict__ isq,
                          const float* __restrict__ sc, const float* __restrict__ sh,
                          const unsigned int* __restrict__ xres,
                          unsigned int* __restrict__ out,
                          const float* __restrict__ Wn, unsigned int* __restrict__ htn,
                          const int* __restrict__ batch, float* __restrict__ pooled,
                          int N) {
    __shared__ float Ws[FUSET ? 4096 : 1];
    __shared__ float hs[(FUSET || FUSEP) ? 16 : 1][(FUSET || FUSEP) ? 68 : 1];
    __shared__ int sgl[FUSEP ? 16 : 1];
    int tid = threadIdx.x;
    int cl = tid & 15;               // channel quad (4 fp8 = 1 dword)
    int nl = tid >> 4;
    int node = (blockIdx.x << 4) + nl;
    bool valid = node < N;
    if (FUSET) {
        const float4* W4p = (const float4*)Wn;
        float4* Ws4 = (float4*)Ws;
        for (int i = tid; i < 1024; i += 256) Ws4[i] = W4p[i];
    }
    float4 A = make_float4(0.f, 0.f, 0.f, 0.f);
    float q = 0.f;
    if (valid) {
        f32x2 a0l = {0.f, 0.f}, a0h = {0.f, 0.f};
        f32x2 a1l = {0.f, 0.f}, a1h = {0.f, 0.f};
        f32x2 a2l = {0.f, 0.f}, a2h = {0.f, 0.f};
        f32x2 a3l = {0.f, 0.f}, a3h = {0.f, 0.f};
        {   // self-loop
            unsigned int u = ht8[node * 16 + cl];
            a0l += fp8_lo(u); a0h += fp8_hi(u);
        }
        int st = rs[node];
        int nch = cnt[node] >> 2;        // int4 chunks (padded)
        const int4* ip = (const int4*)(ssrc + st);
        for (int ch = 0; ch < nch; ch++) {
            int4 s = ip[ch];             // broadcast within group
            unsigned int u0 = ht8[s.x * 16 + cl];
            unsigned int u1 = ht8[s.y * 16 + cl];
            unsigned int u2 = ht8[s.z * 16 + cl];
            unsigned int u3 = ht8[s.w * 16 + cl];
            a0l += fp8_lo(u0); a0h += fp8_hi(u0);
            a1l += fp8_lo(u1); a1h += fp8_hi(u1);
            a2l += fp8_lo(u2); a2h += fp8_hi(u2);
            a3l += fp8_lo(u3); a3h += fp8_hi(u3);
        }
        f32x2 al = (a0l + a1l) + (a2l + a3l);
        f32x2 ah = (a0h + a1h) + (a2h + a3h);
        A = make_float4(al.x, al.y, ah.x, ah.y);
        q = isq[node];
        float4 scv = ((const float4*)sc)[cl];
        float4 shv = ((const float4*)sh)[cl];
        A.x = fmaf(A.x * q, scv.x, shv.x);
        A.y = fmaf(A.y * q, scv.y, shv.y);
        A.z = fmaf(A.z * q, scv.z, shv.z);
        A.w = fmaf(A.w * q, scv.w, shv.w);
        if (MODE < 2) {
            A.x = fmaxf(A.x, 0.f); A.y = fmaxf(A.y, 0.f);
            A.z = fmaxf(A.z, 0.f); A.w = fmaxf(A.w, 0.f);
            if (MODE == 1) {
                uint2 r = ((const uint2*)xres)[node * 16 + cl];
                A.x += u2f(r.x << 16); A.y += u2f(r.x & 0xffff0000u);
                A.z += u2f(r.y << 16); A.w += u2f(r.y & 0xffff0000u);
            }
        }
        if (OUTW) {
            uint2 o;
            o.x = f2bf(A.x) | (f2bf(A.y) << 16);
            o.y = f2bf(A.z) | (f2bf(A.w) << 16);
            ((uint2*)out)[node * 16 + cl] = o;
        }
    }
    if (FUSET || FUSEP) {
        hs[nl][4 * cl + 0] = A.x;
        hs[nl][4 * cl + 1] = A.y;
        hs[nl][4 * cl + 2] = A.z;
        hs[nl][4 * cl + 3] = A.w;
        if (FUSEP && cl == 0) sgl[nl] = valid ? batch[node] : -1;
        __syncthreads();
    }
    if (FUSET) {
        if (valid) {
            const float4* hrow = (const float4*)&hs[nl][0];   // stride 68: 16B-aligned
            float4 acc = make_float4(0.f, 0.f, 0.f, 0.f);
#pragma unroll
            for (int k4 = 0; k4 < 16; k4++) {
                float4 hv = hrow[k4];
                float4 w0 = ((const float4*)&Ws[(4 * k4 + 0) * 64])[cl];
                float4 w1 = ((const float4*)&Ws[(4 * k4 + 1) * 64])[cl];
                float4 w2 = ((const float4*)&Ws[(4 * k4 + 2) * 64])[cl];
                float4 w3 = ((const float4*)&Ws[(4 * k4 + 3) * 64])[cl];
                acc.x = fmaf(hv.x, w0.x, acc.x); acc.y = fmaf(hv.x, w0.y, acc.y);
                acc.z = fmaf(hv.x, w0.z, acc.z); acc.w = fmaf(hv.x, w0.w, acc.w);
                acc.x = fmaf(hv.y, w1.x, acc.x); acc.y = fmaf(hv.y, w1.y, acc.y);
                acc.z = fmaf(hv.y, w1.z, acc.z); acc.w = fmaf(hv.y, w1.w, acc.w);
                acc.x = fmaf(hv.z, w2.x, acc.x); acc.y = fmaf(hv.z, w2.y, acc.y);
                acc.z = fmaf(hv.z, w2.z, acc.z); acc.w = fmaf(hv.z, w2.w, acc.w);
                acc.x = fmaf(hv.w, w3.x, acc.x); acc.y = fmaf(hv.w, w3.y, acc.y);
                acc.z = fmaf(hv.w, w3.z, acc.z); acc.w = fmaf(hv.w, w3.w, acc.w);
            }
            acc.x *= q; acc.y *= q; acc.z *= q; acc.w *= q;
            unsigned int lo = pack_fp8x2(acc.x, acc.y);
            unsigned int hi = pack_fp8x2(acc.z, acc.w);
            htn[node * 16 + cl] = lo | (hi << 16);
        }
    }
    if (FUSEP) {
        if (tid < 64) {
            int c = tid;
            float sum = 0.f;
            int curg = sgl[0];
            for (int r = 0; r < 16; r++) {
                int g = sgl[r];
                if (g != curg) {
                    if (curg >= 0) atomicAdd(&pooled[curg * 64 + c], sum);
                    sum = 0.f;
                    curg = g;
                }
                if (g >= 0) sum += hs[r][c];
            }
            if (curg >= 0) atomicAdd(&pooled[curg * 64 + c], sum);
        }
    }
}

// ---------------- head: mean-divide + MLP + log_softmax (one block per graph) ----------

__device__ inline int lbound(const int* __restrict__ a, int n, int key) {
    int lo = 0, hi = n;
    while (lo < hi) {
        int mid = (lo + hi) >> 1;
        if (a[mid] < key) lo = mid + 1; else hi = mid;
    }
    return lo;
}

__global__ void k_head(const float* __restrict__ pooled, const int* __restrict__ batch,
                       const float* __restrict__ lw1, const float* __restrict__ lb1,
                       const float* __restrict__ lw2, const float* __restrict__ lb2,
                       float* __restrict__ out, int N) {
    __shared__ float w1s[2048];
    __shared__ float ps[64];
    int g = blockIdx.x;
    int c = threadIdx.x;  // 64 threads
    for (int i = c; i < 2048; i += 64) w1s[i] = lw1[i];
    int lo = lbound(batch, N, g);
    int hi = lbound(batch, N, g + 1);
    ps[c] = pooled[g * 64 + c] / fmaxf((float)(hi - lo), 1.0f);
    __syncthreads();
    float l0 = 0.f, l1 = 0.f;
    if (c < 32) {
        float hj = lb1[c];
#pragma unroll
        for (int k = 0; k < 64; k++) hj = fmaf(ps[k], w1s[k * 32 + c], hj);
        hj = fmaxf(hj, 0.f);
        l0 = hj * lw2[c * 2 + 0];
        l1 = hj * lw2[c * 2 + 1];
    }
#pragma unroll
    for (int off = 16; off >= 1; off >>= 1) {
        l0 += __shfl_down(l0, off);
        l1 += __shfl_down(l1, off);
    }
    if (c == 0) {
        l0 += lb2[0]; l1 += lb2[1];
        float mx = fmaxf(l0, l1);
        float lse = mx + logf(expf(l0 - mx) + expf(l1 - mx));
        out[g * 2 + 0] = l0 - lse;
        out[g * 2 + 1] = l1 - lse;
    }
}

// ---------------- launch ----------------

extern "C" void kernel_launch(void* const* d_in, const int* in_sizes, int n_in,
                              void* d_out, int out_size, void* d_ws, size_t ws_size,
                              hipStream_t stream) {
    const float* x   = (const float*)d_in[0];
    const float* W1  = (const float*)d_in[1];
    const float* b1  = (const float*)d_in[2];
    const float* W2  = (const float*)d_in[3];
    const float* b2  = (const float*)d_in[4];
    const float* W3  = (const float*)d_in[5];
    const float* b3  = (const float*)d_in[6];
    const float* W4  = (const float*)d_in[7];
    const float* b4  = (const float*)d_in[8];
    const float* g1  = (const float*)d_in[9];
    const float* be1 = (const float*)d_in[10];
    const float* m1  = (const float*)d_in[11];
    const float* v1  = (const float*)d_in[12];
    const float* g2  = (const float*)d_in[13];
    const float* be2 = (const float*)d_in[14];
    const float* m2  = (const float*)d_in[15];
    const float* v2  = (const float*)d_in[16];
    const float* g3  = (const float*)d_in[17];
    const float* be3 = (const float*)d_in[18];
    const float* m3  = (const float*)d_in[19];
    const float* v3  = (const float*)d_in[20];
    const float* lw1 = (const float*)d_in[21];
    const float* lb1 = (const float*)d_in[22];
    const float* lw2 = (const float*)d_in[23];
    const float* lb2 = (const float*)d_in[24];
    const int* src   = (const int*)d_in[25];
    const int* dst   = (const int*)d_in[26];
    const int* batch = (const int*)d_in[27];

    const int N = in_sizes[0] / 3;
    const int E = in_sizes[25];
    const int G = out_size / 2;

    char* w = (char*)d_ws;
    size_t off = 0;
    auto carve = [&](size_t bytes) -> void* {
        void* p = w + off;
        off = (off + bytes + 255) & ~(size_t)255;
        return p;
    };
    const int nbkt = (N + 255) >> BKT_SHIFT;
    int*   cnt     = (int*)  carve((size_t)N * 4);
    float* isq     = (float*)carve((size_t)N * 4);
    int*   rs      = (int*)  carve((size_t)N * 4);
    int*   bcur    = (int*)  carve(1024 * 4);
    float* scsh    = (float*)carve(8 * 64 * 4);
    int*   ssrc    = (int*)  carve((size_t)nbkt * SS_CAP * 4);
    unsigned int* ebuf = (unsigned int*)carve((size_t)nbkt * BKT_CAP * 4);
    unsigned int* hta = (unsigned int*)carve((size_t)(N + 1) * 64);  // fp8 rows + zero row
    unsigned int* htb = (unsigned int*)carve((size_t)(N + 1) * 64);
    unsigned int* xa = (unsigned int*)carve((size_t)N * 64 * 2);     // bf16 trunk
    unsigned int* xb = (unsigned int*)carve((size_t)N * 64 * 2);
    float* pooled  = (float*)carve((size_t)G * 64 * 4);
    (void)ws_size; (void)n_in;

    const int nbNode4 = (N + 3) / 4;
    const int nbNode16 = (N + 15) / 16;
    const int nbMs = (E + EPB - 1) / EPB;
    float* outp = (float*)d_out;

    // init (prefold + bcur + ht sentinels) + bucket build; zero pooled accumulator
    k_init<<<1 + (nbkt + 255) / 256, 256, 0, stream>>>(bcur, nbkt,
                                  b1, g1, be1, m1, v1, b2, g2, be2, m2, v2,
                                  b3, g3, be3, m3, v3, b4, scsh,
                                  hta + (size_t)N * 16, htb + (size_t)N * 16);
    hipMemsetAsync(pooled, 0, (size_t)G * 64 * 4, stream);
    k_mscat<<<nbMs, MS_THREADS, 0, stream>>>(src, dst, bcur, ebuf, E, nbkt);
    k_bfin<<<nbkt, 1024, 0, stream>>>(ebuf, bcur, cnt, isq, rs, ssrc, N);

    dim3 tb(64, 4);

    // layer 1: x -> hta(fp8); rowwave1 -> xa(bf16) + htb (= fp8(isq * xa @ W2))
    k_transform3<<<nbNode4, tb, 0, stream>>>(x, W1, isq, (unsigned short*)hta, N);
    k_rowwave<0, true, true, false><<<nbNode16, 256, 0, stream>>>(hta, rs, cnt, ssrc, isq,
                                               scsh + 0, scsh + 64, nullptr, xa, W2, htb,
                                               nullptr, nullptr, N);
    // layer 2: rowwave2 -> xb(bf16) (+res xa) + hta (= fp8(isq * xb @ W3))
    k_rowwave<1, true, true, false><<<nbNode16, 256, 0, stream>>>(htb, rs, cnt, ssrc, isq,
                                               scsh + 128, scsh + 192, xa, xb, W3, hta,
                                               nullptr, nullptr, N);
    // layer 3: rowwave3 -> (+res xb, trunk write skipped) + htb (= fp8(isq * x3 @ W4))
    k_rowwave<1, true, false, false><<<nbNode16, 256, 0, stream>>>(hta, rs, cnt, ssrc, isq,
                                               scsh + 256, scsh + 320, xb, nullptr, W4, htb,
                                               nullptr, nullptr, N);
    // layer 4: rowwave4 -> pooled sums directly (no trunk write)
    k_rowwave<2, false, false, true><<<nbNode16, 256, 0, stream>>>(htb, rs, cnt, ssrc, isq,
                                               scsh + 384, scsh + 448, nullptr, nullptr,
                                               nullptr, nullptr, batch, pooled, N);

    // head: divide by counts + MLP + log_softmax
    k_head<<<G, 64, 0, stream>>>(pooled, batch, lw1, lb1, lw2, lb2, outp, N);
}